// Round 14
// baseline (461.045 us; speedup 1.0000x reference)
//
#include <hip/hip_runtime.h>

#define NPNT 4096
#define NSTK 32

typedef _Float16 half8 __attribute__((ext_vector_type(8)));
typedef float f32x4 __attribute__((ext_vector_type(4)));
typedef unsigned long long u64;
typedef unsigned int u32;
typedef unsigned short u16;

// ---------------- workspace layout (floats) ----------------
static const size_t OFF_XT   = 0;          // XT2H/XT2L (f16); M aliases after k_knnpq
static const size_t OFF_P    = 4194304;    // P' compact fp32 [b,16,128,256] = 2097152
                                           //  free half [6291456,8388608) holds PKD/PKI
static const size_t OFF_Q    = 8388608;    // Q' fp32 [b,n,256]
static const size_t OFF_SQD  = 12582912;   // 16384
static const size_t OFF_SPFD = 12599296;   // 16384
static const size_t OFF_WSP  = 12746752;   // W f16 splits (131072 floats) + WDP (196608 floats)
static const size_t OFF_FPS  = 13566208;   // 64 (int)
static const size_t OFF_SD   = 13566272;   // 4096

// ---- u64-key top-10 machinery (key = sortable(d)<<32 | idx; keys distinct) ----
__device__ __forceinline__ void insertK(u64 lk[10], u64 k) {
  if (k >= lk[9]) return;
  lk[9] = k;
#pragma unroll
  for (int j = 9; j > 0; j--) {
    u64 a = lk[j-1], b2 = lk[j];
    bool sw = b2 < a;
    lk[j-1] = sw ? b2 : a;
    lk[j]   = sw ? a : b2;
  }
}

#define CASK(a, b) { u64 _x = (a), _y = (b); bool _s = _y < _x; \
  (a) = _s ? _y : _x; (b) = _s ? _x : _y; }

// merge two sorted-asc 10-lists, keep sorted top-10 into lk.
__device__ __forceinline__ void merge10(u64 lk[10], const u64 b[10]) {
  u64 c[10];
#pragma unroll
  for (int i = 0; i < 10; i++) { u64 t = b[9 - i]; u64 a = lk[i]; c[i] = a < t ? a : t; }
  CASK(c[0], c[5]); CASK(c[1], c[6]); CASK(c[2], c[7]); CASK(c[3], c[8]); CASK(c[4], c[9]);
  CASK(c[0], c[1]); CASK(c[1], c[2]); CASK(c[2], c[3]); CASK(c[3], c[4]);
  CASK(c[0], c[1]); CASK(c[1], c[2]); CASK(c[2], c[3]);
  CASK(c[0], c[1]); CASK(c[1], c[2]);
  CASK(c[0], c[1]);
  CASK(c[5], c[6]); CASK(c[6], c[7]); CASK(c[7], c[8]); CASK(c[8], c[9]);
  CASK(c[5], c[6]); CASK(c[6], c[7]); CASK(c[7], c[8]);
  CASK(c[5], c[6]); CASK(c[6], c[7]);
  CASK(c[5], c[6]);
#pragma unroll
  for (int i = 0; i < 10; i++) lk[i] = c[i];
}

// ---------------- K-PRE: fused {fps | sd | split256 | d2s | splitW | wdperm} ----------------
__global__ __launch_bounds__(256) void k_pre(
    const float* __restrict__ df, const float* __restrict__ sf,
    const float* __restrict__ coor, const float* __restrict__ dnW,
    const float* __restrict__ d2sw, const float* __restrict__ d2scb,
    const float* __restrict__ d2sg, const float* __restrict__ d2sbt,
    const float* __restrict__ dsw,
    _Float16* __restrict__ XH, _Float16* __restrict__ XL, float* __restrict__ sqd,
    _Float16* __restrict__ WPh, _Float16* __restrict__ WPl,
    _Float16* __restrict__ WQh, _Float16* __restrict__ WQl,
    float* __restrict__ WDP, float* __restrict__ SD,
    float* __restrict__ spfd, int* __restrict__ fpsidx, float* __restrict__ out2) {
  __shared__ __align__(16) char SMEM[46080];
  const int bid = blockIdx.x;
  const int t = threadIdx.x;

  if (bid < 4) {
    // ---- FPS + out2 gather ----
    int b = bid;
    float (*X)[132] = (float (*)[132])SMEM;
    float* dist = (float*)(SMEM + 16896);
    int* far_s  = (int*)(SMEM + 17024);
    int* sel    = (int*)(SMEM + 17028);
    for (int idx = t; idx < 32 * 32; idx += 256) {
      int r = idx >> 5, q = idx & 31;
      *(float4*)&X[r][q * 4] = *(const float4*)&coor[((size_t)b * 32 + r) * 128 + q * 4];
    }
    if (t < 32) dist[t] = 1e10f;
    if (t == 0) *far_s = 0;
    __syncthreads();
    for (int it = 0; it < 16; it++) {
      int far = *far_s;
      if (t == 0) sel[it] = far;
      if (t < 32) {
        float d = 0.0f;
        for (int c = 0; c < 128; c++) { float dd = X[t][c] - X[far][c]; d = fmaf(dd, dd, d); }
        float dm = dist[t];
        dist[t] = d < dm ? d : dm;
      }
      __syncthreads();
      if (t == 0) {
        float best = -1.0f; int bi = 0;
        for (int m = 0; m < 32; m++) if (dist[m] > best) { best = dist[m]; bi = m; }
        *far_s = bi;
      }
      __syncthreads();
    }
    if (t < 16) fpsidx[b * 16 + t] = sel[t];
    __syncthreads();
    for (int idx = t; idx < 16 * 32; idx += 256) {
      int j = idx >> 5, q = idx & 31;
      *(float4*)&out2[((size_t)b * 16 + j) * 128 + q * 4] = *(const float4*)&X[sel[j]][q * 4];
    }
  } else if (bid < 8) {
    // ---- SD ----
    int b = bid - 4;
    float* Xs = (float*)SMEM;
    for (int k = t; k < 1024; k += 256)
      *(float4*)&Xs[k * 4] = *(const float4*)&sf[(size_t)b * 4096 + k * 4];
    __syncthreads();
#pragma unroll
    for (int rep = 0; rep < 4; rep++) {
      int p = t + rep * 256;
      int s = p >> 5, u = p & 31;
      float acc = 0.0f;
      for (int c = 0; c < 128; c++) {
        float d = Xs[c * 32 + s] - Xs[c * 32 + u];
        acc = fmaf(d, d, acc);
      }
      SD[(size_t)b * 1024 + p] = acc;
    }
  } else if (bid < 264) {
    // ---- split256 ----
    int idx0 = bid - 8;
    int b = idx0 & 3, n0 = (idx0 >> 2) * 64;
    int s0 = n0 >> 7;
    float (*T)[68] = (float (*)[68])SMEM;
    _Float16* Sh = (_Float16*)(SMEM + 34816);
    _Float16* Sl = (_Float16*)(SMEM + 35072);
    {
      int c = t >> 1, nh = (t & 1) * 32;
      const float* src = &df[((size_t)b * 128 + c) * NPNT + n0 + nh];
#pragma unroll
      for (int j = 0; j < 8; j++) *(float4*)&T[c][nh + j * 4] = *(const float4*)&src[j * 4];
    }
    if (t < 128) {
      float x = sf[((size_t)b * 128 + t) * NSTK + s0];
      _Float16 hi = (_Float16)x;
      Sh[t] = hi; Sl[t] = (_Float16)(x - (float)hi);
    }
    __syncthreads();
    {
      int n = t >> 2, cseg = (t & 3) * 32;
      size_t base = ((size_t)b * NPNT + n0 + n) * 256;
      float s = 0.0f;
#pragma unroll
      for (int k = 0; k < 4; k++) {
        half8 hv, lv, shv, slv;
#pragma unroll
        for (int e = 0; e < 8; e++) {
          float x = T[cseg + k * 8 + e][n];
          s = fmaf(x, x, s);
          _Float16 hi = (_Float16)x;
          hv[e] = hi; lv[e] = (_Float16)(x - (float)hi);
          shv[e] = Sh[cseg + k * 8 + e];
          slv[e] = Sl[cseg + k * 8 + e];
        }
        *(half8*)&XH[base + cseg + k * 8] = hv;
        *(half8*)&XL[base + cseg + k * 8] = lv;
        *(half8*)&XH[base + 128 + cseg + k * 8] = shv;
        *(half8*)&XL[base + 128 + cseg + k * 8] = slv;
      }
      s += __shfl_xor(s, 1);
      s += __shfl_xor(s, 2);
      if ((t & 3) == 0) sqd[(size_t)b * NPNT + n0 + n] = s;
    }
  } else if (bid < 520) {
    // ---- d2s ----
    int idx0 = bid - 264;
    int b = idx0 & 3, o0 = ((idx0 >> 2) & 1) * 64, s = idx0 >> 3;
    int n0 = s * 128;
    float (*A)[64]   = (float (*)[64])SMEM;
    float (*Bs)[132] = (float (*)[132])(SMEM + 24576);
    float (*Dr)[17]  = (float (*)[17])(SMEM + 41472);
    float acc[4][8];
#pragma unroll
    for (int i = 0; i < 4; i++)
#pragma unroll
      for (int j = 0; j < 8; j++) acc[i][j] = 0.0f;
    int tn = t & 15, to = t >> 4;
    for (int ic = 0; ic < 128; ic += 32) {
      {
        int ol = t >> 2, q = t & 3;
        const float* src = &d2sw[((size_t)(o0 + ol) * 128 + ic) * 3 + q * 24];
#pragma unroll
        for (int r = 0; r < 6; r++) {
          float4 v = *(const float4*)&src[r * 4];
          int e = q * 24 + r * 4;
          A[e+0][ol] = v.x; A[e+1][ol] = v.y; A[e+2][ol] = v.z; A[e+3][ol] = v.w;
        }
      }
      for (int idx = t; idx < 32 * 33; idx += 256) {
        int row = idx / 33, f4 = idx % 33;
        int nb = n0 + f4 * 4;
        const float* srow = &df[((size_t)b * 128 + ic + row) * NPNT];
        float4 v;
        if (nb + 3 < NPNT) v = *(const float4*)&srow[nb];
        else {
          v.x = srow[nb   < NPNT ? nb   : NPNT-1];
          v.y = srow[nb+1 < NPNT ? nb+1 : NPNT-1];
          v.z = srow[nb+2 < NPNT ? nb+2 : NPNT-1];
          v.w = srow[nb+3 < NPNT ? nb+3 : NPNT-1];
        }
        *(float4*)&Bs[row][f4 * 4] = v;
      }
      __syncthreads();
#pragma unroll 2
      for (int ii = 0; ii < 32; ii++) {
        float bv[12];
        *(float4*)&bv[0] = *(const float4*)&Bs[ii][tn * 8];
        *(float4*)&bv[4] = *(const float4*)&Bs[ii][tn * 8 + 4];
        *(float4*)&bv[8] = *(const float4*)&Bs[ii][tn * 8 + 8];
#pragma unroll
        for (int kw = 0; kw < 3; kw++) {
          float4 av = *(const float4*)&A[ii * 3 + kw][to * 4];
#pragma unroll
          for (int j = 0; j < 8; j++) {
            float bvj = bv[kw + j];
            acc[0][j] = fmaf(av.x, bvj, acc[0][j]);
            acc[1][j] = fmaf(av.y, bvj, acc[1][j]);
            acc[2][j] = fmaf(av.z, bvj, acc[2][j]);
            acc[3][j] = fmaf(av.w, bvj, acc[3][j]);
          }
        }
      }
      __syncthreads();
    }
#pragma unroll
    for (int i = 0; i < 4; i++) {
      int o = o0 + to * 4 + i;
      float gg = d2sg[o], bb = d2scb[o], bo = d2sbt[o];
      float m = 0.0f;
#pragma unroll
      for (int j = 0; j < 8; j++) {
        int p = tn * 8 + j;
        if (p < 126) {
          float v = fmaf(gg, acc[i][j] + bb, bo);
          v = v > 0.0f ? v : 0.0f;
          m = v > m ? v : m;
        }
      }
      Dr[to * 4 + i][tn] = m;
    }
    __syncthreads();
    if (t < 64) {
      float m = 0.0f;
#pragma unroll
      for (int k = 0; k < 16; k++) m = Dr[t][k] > m ? Dr[t][k] : m;
      spfd[((size_t)b * 128 + o0 + t) * NSTK + s] = m;
    }
  } else if (bid < 776) {
    // ---- splitW ----
    int k = bid - 520, o = t;
    float w1 = dnW[(size_t)k * 256 + o];
    float w2 = dnW[(size_t)(k + 256) * 256 + o];
    float p = w1 - w2;
    _Float16 ph = (_Float16)p;  WPh[(size_t)o * 256 + k] = ph;
    WPl[(size_t)o * 256 + k] = (_Float16)(p - (float)ph);
    _Float16 qh = (_Float16)w2; WQh[(size_t)o * 256 + k] = qh;
    WQl[(size_t)o * 256 + k] = (_Float16)(w2 - (float)qh);
  } else {
    // ---- wdperm ----
    int o = bid - 776;
    const float* src = &dsw[(size_t)o * 768];
    float* dst = &WDP[(size_t)o * 768];
#pragma unroll
    for (int kw = 0; kw < 3; kw++)
      dst[kw * 256 + t] = src[t * 3 + kw];
  }
}

// ---------------- K3: sparse mono2 — graph + P/Q + combine, 32 blocks ----------------
__global__ __launch_bounds__(256) void k_sparse_mono2(const float* __restrict__ sf,
    const float* __restrict__ spfd, const int* __restrict__ fps, const float* __restrict__ W,
    const float* __restrict__ g, const float* __restrict__ cb, const float* __restrict__ bt,
    float* __restrict__ out0) {
  int b = blockIdx.x, og = blockIdx.y;
  int t = threadIdx.x;
  __shared__ float X[32][260];
  __shared__ float Qs[32][33];
  __shared__ float Pl[16][33];
  __shared__ float sq[32];
  __shared__ float D[32][33];
  __shared__ int idxs_s[64];
  __shared__ int fps_s[16];
  for (int idx = t; idx < 32 * 256; idx += 256) {
    int n = idx >> 8, c = idx & 255;
    X[n][c] = (c < 128) ? sf[((size_t)b * 128 + c) * NSTK + n]
                        : spfd[((size_t)b * 128 + (c - 128)) * NSTK + n];
  }
  if (t < 16) fps_s[t] = fps[b * 16 + t];
  __syncthreads();
  if (t < 32) {
    float s = 0.0f;
    for (int c = 0; c < 256; c++) s = fmaf(X[t][c], X[t][c], s);
    sq[t] = s;
  }
  __syncthreads();
  {
    int n = t >> 3;
    for (int mg = 0; mg < 4; mg++) {
      int m = (t & 7) + mg * 8;
      float dot = 0.0f;
      for (int c = 0; c < 256; c++) dot = fmaf(X[n][c], X[m][c], dot);
      D[n][m] = (sq[n] - 2.0f * dot) + sq[m];
    }
  }
  __syncthreads();
  if (t < 32) {
    float d0 = 1e30f, d1 = 1e30f; int i0 = 0, i1 = 0;
    for (int m = 0; m < 32; m++) {
      float d = D[t][m];
      if (d < d0) { d1 = d0; i1 = i0; d0 = d; i0 = m; }
      else if (d < d1) { d1 = d; i1 = m; }
    }
    idxs_s[t * 2 + 0] = i0;
    idxs_s[t * 2 + 1] = i1;
  }
  const int ol = t & 31, sg = t >> 5;
  const int o = og * 32 + ol;
  {
    float acc[4] = {0.0f, 0.0f, 0.0f, 0.0f};
    for (int c4 = 0; c4 < 64; c4++) {
      int c = c4 * 4;
      float w0 = W[(size_t)(c + 256) * 256 + o];
      float w1 = W[(size_t)(c + 257) * 256 + o];
      float w2 = W[(size_t)(c + 258) * 256 + o];
      float w3 = W[(size_t)(c + 259) * 256 + o];
#pragma unroll
      for (int k = 0; k < 4; k++) {
        float4 xv = *(const float4*)&X[sg * 4 + k][c];
        acc[k] = fmaf(xv.x, w0, acc[k]);
        acc[k] = fmaf(xv.y, w1, acc[k]);
        acc[k] = fmaf(xv.z, w2, acc[k]);
        acc[k] = fmaf(xv.w, w3, acc[k]);
      }
    }
#pragma unroll
    for (int k = 0; k < 4; k++) Qs[sg * 4 + k][ol] = acc[k];
  }
  if (sg < 4) {
    int fs[4];
#pragma unroll
    for (int k = 0; k < 4; k++) fs[k] = fps_s[sg * 4 + k];
    float acc[4] = {0.0f, 0.0f, 0.0f, 0.0f};
    for (int c4 = 0; c4 < 64; c4++) {
      int c = c4 * 4;
      float p0 = W[(size_t)(c + 0) * 256 + o] - W[(size_t)(c + 256) * 256 + o];
      float p1 = W[(size_t)(c + 1) * 256 + o] - W[(size_t)(c + 257) * 256 + o];
      float p2 = W[(size_t)(c + 2) * 256 + o] - W[(size_t)(c + 258) * 256 + o];
      float p3 = W[(size_t)(c + 3) * 256 + o] - W[(size_t)(c + 259) * 256 + o];
#pragma unroll
      for (int k = 0; k < 4; k++) {
        float4 xv = *(const float4*)&X[fs[k]][c];
        acc[k] = fmaf(xv.x, p0, acc[k]);
        acc[k] = fmaf(xv.y, p1, acc[k]);
        acc[k] = fmaf(xv.z, p2, acc[k]);
        acc[k] = fmaf(xv.w, p3, acc[k]);
      }
    }
#pragma unroll
    for (int k = 0; k < 4; k++) Pl[sg * 4 + k][ol] = acc[k];
  }
  __syncthreads();
  if (t < 32) {
    int oo = og * 32 + t;
    float gg = g[oo], bb = cb[oo], bo = bt[oo];
#pragma unroll
    for (int j = 0; j < 16; j++) {
      int n = fps_s[j];
      int i0 = idxs_s[n * 2 + 0], i1 = idxs_s[n * 2 + 1];
      float p = Pl[j][t];
      float h0 = fmaf(gg, p + Qs[i0][t] + bb, bo); h0 = h0 > 0.0f ? h0 : 0.0f;
      float h1 = fmaf(gg, p + Qs[i1][t] + bb, bo); h1 = h1 > 0.0f ? h1 : 0.0f;
      out0[((size_t)b * 256 + oo) * 16 + j] = h0 > h1 ? h0 : h1;
    }
  }
}

// ---------------- K4+K5 fused: role-split, 4:1 interleave, condensed pq (512 blk x 2 units) ----
// R14: a resident pq block displaces a knn block (8 slots/CU, LDS-capped). Halve pq
// blocks (each does 2 bx units) -> knn keeps ~6.4 slots/CU instead of 5.3; pq still
// has 512-way parallelism for its memory-bound work.
#define STAGE(ch2_, p_) { \
  int srow = t >> 2, scol = (t & 3) * 16; \
  size_t gp = (bofs + (size_t)(m0 + (ch2_) * 64 + srow)) * 256 + (p_) * 64 + scol; \
  float4 gh0 = *(const float4*)&XH[gp]; float4 gh1 = *(const float4*)&XH[gp + 8]; \
  float4 gl0 = *(const float4*)&XL[gp]; float4 gl1 = *(const float4*)&XL[gp + 8]; \
  int lo = srow * 72 + scol; \
  *(float4*)&BshH[lo] = gh0; *(float4*)&BshH[lo + 8] = gh1; \
  *(float4*)&BshL[lo] = gl0; *(float4*)&BshL[lo + 8] = gl1; }

#define DWU(wv_, r_, c_) DwU[(((wv_) * 16 + (r_)) * 68) + (c_)]

__global__ __launch_bounds__(256, 4) void k_knnpq(const _Float16* __restrict__ XH,
    const _Float16* __restrict__ XL, const float* __restrict__ sqd, const float* __restrict__ SD,
    const int* __restrict__ fps,
    const _Float16* __restrict__ WPh, const _Float16* __restrict__ WPl,
    const _Float16* __restrict__ WQh, const _Float16* __restrict__ WQl,
    const float* __restrict__ g, const float* __restrict__ cb, const float* __restrict__ bt,
    u32* __restrict__ pkd, u16* __restrict__ pki,
    float* __restrict__ Pc, float* __restrict__ Qp) {
  const int bid0 = blockIdx.x;
  const int t = threadIdx.x;
  const int w = t >> 6, L = t & 63;
  const int c15 = L & 15, q = L >> 4;
  f32x4 zz = {0.0f, 0.0f, 0.0f, 0.0f};

  __shared__ __align__(16) char SMEM[18432];

  const int rrem = bid0 % 5;
  const bool is_knn = (rrem < 4);

  if (is_knn) {
    // ================= knn role (byte-identical logic to R13) ================
    const int bid = (bid0 / 5) * 4 + rrem;   // 0..2047 bijective
    const int h = bid & 15, rb = (bid >> 4) & 31, b = bid >> 9;
    const int jst = rb >> 1;
    const int ph = (rb & 1) * 64;
    const int s_stk = fps[b * 16 + jst];
    const int nsrc = s_stk * 128 + ph + w * 16;
    const int rc0 = rb * 64 + w * 16;
    const size_t bofs = (size_t)b * NPNT;

    _Float16* const BshH = (_Float16*)SMEM;
    _Float16* const BshL = (_Float16*)(SMEM + 64 * 72 * 2);
    unsigned* const DwU = (unsigned*)SMEM;

    half8 ah[4], al[4];
    {
      const _Float16* ap  = XH + (bofs + nsrc + c15) * 256 + q * 8;
      const _Float16* apl = XL + (bofs + nsrc + c15) * 256 + q * 8;
#pragma unroll
      for (int ch = 0; ch < 4; ch++) {
        ah[ch] = *(const half8*)(ap + ch * 32);
        al[ch] = *(const half8*)(apl + ch * 32);
      }
    }
    float snr[4];
#pragma unroll
    for (int r = 0; r < 4; r++) snr[r] = sqd[bofs + nsrc + q * 4 + r];

    u64 lk[10];
#pragma unroll
    for (int j = 0; j < 10; j++) lk[j] = ~0ull;

    const bool own_here = ((s_stk >> 1) == h);
    const int r_sel = L >> 2, sl = L & 3;
    const int u0 = own_here ? s_stk : (h * 2);
    const int u1 = own_here ? (s_stk ^ 1) : (h * 2 + 1);

#pragma unroll 1
    for (int it = 0; it < 2; it++) {
      const int u = (it == 0) ? u0 : u1;
      const int m0 = u * 128;
      const float SDv = SD[((size_t)b * 32 + s_stk) * 32 + u];

#pragma unroll 1
      for (int ch2 = 0; ch2 < 2; ch2++) {
        float smv[4];
#pragma unroll
        for (int cg = 0; cg < 4; cg++) smv[cg] = sqd[bofs + m0 + ch2 * 64 + cg * 16 + c15];

        f32x4 acc[4];
#pragma unroll
        for (int cg = 0; cg < 4; cg++) acc[cg] = zz;

        __syncthreads();
        STAGE(ch2, 0);
        __syncthreads();
#pragma unroll
        for (int chl = 0; chl < 2; chl++) {
#pragma unroll
          for (int cg = 0; cg < 4; cg++) {
            int lo = (cg * 16 + c15) * 72 + chl * 32 + q * 8;
            half8 bh = *(const half8*)&BshH[lo];
            half8 bl = *(const half8*)&BshL[lo];
            acc[cg] = __builtin_amdgcn_mfma_f32_16x16x32_f16(ah[chl], bh, acc[cg], 0, 0, 0);
            acc[cg] = __builtin_amdgcn_mfma_f32_16x16x32_f16(ah[chl], bl, acc[cg], 0, 0, 0);
            acc[cg] = __builtin_amdgcn_mfma_f32_16x16x32_f16(al[chl], bh, acc[cg], 0, 0, 0);
          }
        }
        __syncthreads();
        STAGE(ch2, 1);
        __syncthreads();
#pragma unroll
        for (int chl = 0; chl < 2; chl++) {
#pragma unroll
          for (int cg = 0; cg < 4; cg++) {
            int lo = (cg * 16 + c15) * 72 + chl * 32 + q * 8;
            half8 bh = *(const half8*)&BshH[lo];
            half8 bl = *(const half8*)&BshL[lo];
            acc[cg] = __builtin_amdgcn_mfma_f32_16x16x32_f16(ah[2 + chl], bh, acc[cg], 0, 0, 0);
            acc[cg] = __builtin_amdgcn_mfma_f32_16x16x32_f16(ah[2 + chl], bl, acc[cg], 0, 0, 0);
            acc[cg] = __builtin_amdgcn_mfma_f32_16x16x32_f16(al[2 + chl], bh, acc[cg], 0, 0, 0);
          }
        }
        __syncthreads();

#pragma unroll
        for (int cg = 0; cg < 4; cg++) {
          float basec = SDv + smv[cg];
#pragma unroll
          for (int r = 0; r < 4; r++) {
            float d = fmaf(-2.0f, acc[cg][r], snr[r] + basec);
            unsigned uu = __float_as_uint(d);
            unsigned kk = uu ^ ((unsigned)((int)uu >> 31) | 0x80000000u);
            DWU(w, q * 4 + r, cg * 16 + c15) = kk;
          }
        }
#pragma unroll
        for (int jj = 0; jj < 4; jj++) {
          uint4 kv = *(const uint4*)&DWU(w, r_sel, jj * 16 + sl * 4);
          int ib = m0 + ch2 * 64 + jj * 16 + sl * 4;
          insertK(lk, ((u64)kv.x << 32) | (unsigned)(ib + 0));
          insertK(lk, ((u64)kv.y << 32) | (unsigned)(ib + 1));
          insertK(lk, ((u64)kv.z << 32) | (unsigned)(ib + 2));
          insertK(lk, ((u64)kv.w << 32) | (unsigned)(ib + 3));
        }
      }
    }

#pragma unroll
    for (int m = 1; m <= 2; m <<= 1) {
      u64 o[10];
#pragma unroll
      for (int j = 0; j < 10; j++) o[j] = __shfl_xor(lk[j], m);
      merge10(lk, o);
    }
    if (sl == 0) {
      size_t row = (size_t)b * 2048 + rc0 + r_sel;
      u32* dk = &pkd[(row * 16 + h) * 10];
      u16* di = &pki[(row * 16 + h) * 10];
#pragma unroll
      for (int j = 0; j < 10; j++) {
        dk[j] = (u32)(lk[j] >> 32);
        di[j] = (u16)(lk[j] & 0xffffull);
      }
    }
  } else {
    // ================= pq role: 512 blocks, each handles 2 consecutive bx units ==========
    const int pq_idx = bid0 / 5;             // 0..511 bijective
#pragma unroll 1
    for (int half = 0; half < 2; half++) {
      const int bid2 = pq_idx * 2 + half;    // 0..1023
      const int bx = bid2 & 127, by = (bid2 >> 7) & 1, b = bid2 >> 8;
      const int ow = by * 128 + (w >> 1) * 64;
      const size_t bofs = (size_t)b * NPNT;

      {
        const int nw = bx * 32 + (w & 1) * 16;
        f32x4 accQ[4];
#pragma unroll
        for (int cg = 0; cg < 4; cg++) accQ[cg] = zz;
        const _Float16* ap  = XH + (bofs + nw + c15) * 256 + q * 8;
        const _Float16* apl = XL + (bofs + nw + c15) * 256 + q * 8;
#pragma unroll
        for (int ch = 0; ch < 8; ch++) {
          half8 a_h = *(const half8*)(ap + ch * 32);
          half8 a_l = *(const half8*)(apl + ch * 32);
#pragma unroll
          for (int cg = 0; cg < 4; cg++) {
            size_t wb = (size_t)(ow + cg * 16 + c15) * 256 + ch * 32 + q * 8;
            half8 bqh = *(const half8*)(WQh + wb);
            half8 bql = *(const half8*)(WQl + wb);
            accQ[cg] = __builtin_amdgcn_mfma_f32_16x16x32_f16(a_h, bqh, accQ[cg], 0, 0, 0);
            accQ[cg] = __builtin_amdgcn_mfma_f32_16x16x32_f16(a_h, bql, accQ[cg], 0, 0, 0);
            accQ[cg] = __builtin_amdgcn_mfma_f32_16x16x32_f16(a_l, bqh, accQ[cg], 0, 0, 0);
          }
        }
#pragma unroll
        for (int cg = 0; cg < 4; cg++) {
          int o = ow + cg * 16 + c15;
          float gg = g[o];
#pragma unroll
          for (int r = 0; r < 4; r++) {
            Qp[(bofs + nw + q * 4 + r) * 256 + o] = gg * accQ[cg][r];
          }
        }
      }

      if (bx < 64) {
        const int m0 = bx * 32 + (w & 1) * 16;
        const int jst = m0 >> 7;
        const int pbase = m0 & 127;
        const int nsrc = fps[b * 16 + jst] * 128 + pbase;
        f32x4 accP[4];
#pragma unroll
        for (int cg = 0; cg < 4; cg++) accP[cg] = zz;
        const _Float16* ap  = XH + (bofs + nsrc + c15) * 256 + q * 8;
        const _Float16* apl = XL + (bofs + nsrc + c15) * 256 + q * 8;
#pragma unroll
        for (int ch = 0; ch < 8; ch++) {
          half8 a_h = *(const half8*)(ap + ch * 32);
          half8 a_l = *(const half8*)(apl + ch * 32);
#pragma unroll
          for (int cg = 0; cg < 4; cg++) {
            size_t wb = (size_t)(ow + cg * 16 + c15) * 256 + ch * 32 + q * 8;
            half8 bph = *(const half8*)(WPh + wb);
            half8 bpl = *(const half8*)(WPl + wb);
            accP[cg] = __builtin_amdgcn_mfma_f32_16x16x32_f16(a_h, bph, accP[cg], 0, 0, 0);
            accP[cg] = __builtin_amdgcn_mfma_f32_16x16x32_f16(a_h, bpl, accP[cg], 0, 0, 0);
            accP[cg] = __builtin_amdgcn_mfma_f32_16x16x32_f16(a_l, bph, accP[cg], 0, 0, 0);
          }
        }
#pragma unroll
        for (int cg = 0; cg < 4; cg++) {
          int o = ow + cg * 16 + c15;
          float gg = g[o], bb = cb[o], bo = bt[o];
#pragma unroll
          for (int r = 0; r < 4; r++) {
            Pc[(((size_t)b * 16 + jst) * 128 + pbase + q * 4 + r) * 256 + o] =
                fmaf(gg, accP[cg][r] + bb, bo);
          }
        }
      }
    }
  }
}

// ---------------- K6: build M — fused 16-list merge + max-gather ----------------
__global__ __launch_bounds__(256) void k_build_M(const float* __restrict__ Pc, const float* __restrict__ Qp,
    const u32* __restrict__ pkd, const u16* __restrict__ pki, float* __restrict__ M) {
  int pc = blockIdx.x, j = blockIdx.y, b = blockIdx.z;
  int t = threadIdx.x;
  __shared__ int knn_s[16][10];
  {
    int rr = t >> 4, ll = t & 15;
    size_t row = (size_t)b * 2048 + j * 128 + pc * 16 + rr;
    const u32* kd = &pkd[(row * 16 + ll) * 10];
    const u16* ki = &pki[(row * 16 + ll) * 10];
    u64 lk[10];
#pragma unroll
    for (int jj = 0; jj < 10; jj++) lk[jj] = ((u64)kd[jj] << 32) | (u64)ki[jj];
#pragma unroll
    for (int m = 1; m <= 8; m <<= 1) {
      u64 o[10];
#pragma unroll
      for (int jj = 0; jj < 10; jj++) o[jj] = __shfl_xor(lk[jj], m);
      merge10(lk, o);
    }
    if (ll == 0) {
#pragma unroll
      for (int jj = 0; jj < 10; jj++) knn_s[rr][jj] = (int)(lk[jj] & 0xffffull);
    }
  }
  __syncthreads();
#pragma unroll 1
  for (int pi = 0; pi < 16; pi++) {
    size_t m = ((size_t)b * 16 + j) * 128 + pc * 16 + pi;
    float pv = Pc[m * 256 + t];
    float mx = 0.0f;
#pragma unroll
    for (int k = 0; k < 10; k++) {
      float qv = Qp[((size_t)b * NPNT + knn_s[pi][k]) * 256 + t];
      float h = pv + qv;
      mx = h > mx ? h : mx;
    }
    M[m * 256 + t] = mx;
  }
}

// ---------------- K7: downsample GEMM (K-permuted: A=WDP, B=M slices) ----------------
__global__ __launch_bounds__(256) void k_ds_gemm(const float* __restrict__ WDP, const float* __restrict__ M,
    const float* __restrict__ cb, const float* __restrict__ g, const float* __restrict__ bt,
    float* __restrict__ out1) {
  int j = blockIdx.x, o0 = blockIdx.y * 64, b = blockIdx.z;
  int j0 = j * 64;
  int t = threadIdx.x;
  __shared__ float A[32][68];
  __shared__ float Bs[32][68];
  float acc[4][4];
#pragma unroll
  for (int i = 0; i < 4; i++)
#pragma unroll
    for (int jj = 0; jj < 4; jj++) acc[i][jj] = 0.0f;
  int tj = t & 15, to = t >> 4;
  for (int kc = 0; kc < 768; kc += 32) {
    {
      int ol = t >> 2, q = t & 3;
      const float* src = &WDP[(size_t)(o0 + ol) * 768 + kc + q * 8];
      float4 v0 = *(const float4*)src, v1 = *(const float4*)(src + 4);
      int cc = q * 8;
      A[cc+0][ol] = v0.x; A[cc+1][ol] = v0.y; A[cc+2][ol] = v0.z; A[cc+3][ol] = v0.w;
      A[cc+4][ol] = v1.x; A[cc+5][ol] = v1.y; A[cc+6][ol] = v1.z; A[cc+7][ol] = v1.w;
    }
    {
      int jl = t >> 2, q = t & 3;
      int kw = kc >> 8, cbl = (kc & 255) + q * 8;
      int p = 2 * jl - 1 + kw;
      float4 v0, v1;
      if (p >= 0) {
        const float* src = &M[(((size_t)b * 16 + j) * 128 + p) * 256 + cbl];
        v0 = *(const float4*)src; v1 = *(const float4*)(src + 4);
      } else {
        v0.x = v0.y = v0.z = v0.w = 0.0f; v1 = v0;
      }
      int cc = q * 8;
      Bs[cc+0][jl] = v0.x; Bs[cc+1][jl] = v0.y; Bs[cc+2][jl] = v0.z; Bs[cc+3][jl] = v0.w;
      Bs[cc+4][jl] = v1.x; Bs[cc+5][jl] = v1.y; Bs[cc+6][jl] = v1.z; Bs[cc+7][jl] = v1.w;
    }
    __syncthreads();
#pragma unroll 4
    for (int k = 0; k < 32; k++) {
      float4 a = *(const float4*)&A[k][to * 4];
      float4 bv = *(const float4*)&Bs[k][tj * 4];
      float av[4] = {a.x, a.y, a.z, a.w};
      float bb[4] = {bv.x, bv.y, bv.z, bv.w};
#pragma unroll
      for (int i = 0; i < 4; i++)
#pragma unroll
        for (int jj = 0; jj < 4; jj++)
          acc[i][jj] = fmaf(av[i], bb[jj], acc[i][jj]);
    }
    __syncthreads();
  }
#pragma unroll
  for (int i = 0; i < 4; i++) {
    int o = o0 + to * 4 + i;
    float gg = g[o], bb = cb[o], bo = bt[o];
    float4 v;
    float x0 = fmaf(gg, acc[i][0] + bb, bo); v.x = x0 > 0.0f ? x0 : 0.0f;
    float x1 = fmaf(gg, acc[i][1] + bb, bo); v.y = x1 > 0.0f ? x1 : 0.0f;
    float x2 = fmaf(gg, acc[i][2] + bb, bo); v.z = x2 > 0.0f ? x2 : 0.0f;
    float x3 = fmaf(gg, acc[i][3] + bb, bo); v.w = x3 > 0.0f ? x3 : 0.0f;
    *(float4*)&out1[((size_t)b * 256 + o) * 1024 + j0 + tj * 4] = v;
  }
}

extern "C" void kernel_launch(void* const* d_in, const int* in_sizes, int n_in,
                              void* d_out, int out_size, void* d_ws, size_t ws_size,
                              hipStream_t stream) {
  (void)in_sizes; (void)n_in; (void)out_size; (void)ws_size;
  const float* sf    = (const float*)d_in[0];
  const float* df    = (const float*)d_in[1];
  const float* coor  = (const float*)d_in[2];
  const float* d2sw  = (const float*)d_in[3];
  const float* d2sb  = (const float*)d_in[4];
  const float* d2sg  = (const float*)d_in[5];
  const float* d2sbt = (const float*)d_in[6];
  const float* spW   = (const float*)d_in[7];
  const float* spb   = (const float*)d_in[8];
  const float* spg   = (const float*)d_in[9];
  const float* spbt  = (const float*)d_in[10];
  const float* dnW   = (const float*)d_in[11];
  const float* dnb   = (const float*)d_in[12];
  const float* dng   = (const float*)d_in[13];
  const float* dnbt  = (const float*)d_in[14];
  const float* dsw   = (const float*)d_in[15];
  const float* dsb   = (const float*)d_in[16];
  const float* dsg   = (const float*)d_in[17];
  const float* dsbt  = (const float*)d_in[18];

  float* ws   = (float*)d_ws;
  float* Pc   = ws + OFF_P;
  float* Qp   = ws + OFF_Q;
  float* SQD  = ws + OFF_SQD;
  float* SPFD = ws + OFF_SPFD;
  int*   FPS  = (int*)(ws + OFF_FPS);
  float* SD   = ws + OFF_SD;
  _Float16* XT2H = (_Float16*)(ws + OFF_XT);
  _Float16* XT2L = XT2H + (size_t)4 * NPNT * 256;
  float* Mb = ws + OFF_XT;     // M aliases XT region (XT dead after k_knnpq)
  _Float16* WPh = (_Float16*)(ws + OFF_WSP);
  _Float16* WPl = WPh + 65536;
  _Float16* WQh = WPh + 131072;
  _Float16* WQl = WPh + 196608;
  float* WDP = ws + OFF_WSP + 131072;
  u32* PKD = (u32*)(ws + OFF_P + 2097152);
  u16* PKI = (u16*)(ws + OFF_P + 2097152 + 1310720);

  float* out0 = (float*)d_out;
  float* out1 = out0 + 16384;
  float* out2 = out1 + 1048576;

  k_pre<<<dim3(1032), 256, 0, stream>>>(df, sf, coor, dnW, d2sw, d2sb, d2sg, d2sbt, dsw,
                                        XT2H, XT2L, SQD, WPh, WPl, WQh, WQl, WDP, SD,
                                        SPFD, FPS, out2);
  k_sparse_mono2<<<dim3(4, 8), 256, 0, stream>>>(sf, SPFD, FPS, spW, spg, spb, spbt, out0);
  k_knnpq<<<dim3(2560), 256, 0, stream>>>(XT2H, XT2L, SQD, SD, FPS,
                                          WPh, WPl, WQh, WQl, dng, dnb, dnbt,
                                          PKD, PKI, Pc, Qp);
  k_build_M<<<dim3(8, 16, 4), 256, 0, stream>>>(Pc, Qp, PKD, PKI, Mb);
  k_ds_gemm<<<dim3(16, 4, 4), 256, 0, stream>>>(WDP, Mb, dsb, dsg, dsbt, out1);
}

// Round 16
// 374.326 us; speedup vs baseline: 1.2317x; 1.2317x over previous
//
#include <hip/hip_runtime.h>

#define NPNT 4096
#define NSTK 32

typedef _Float16 half8 __attribute__((ext_vector_type(8)));
typedef float f32x4 __attribute__((ext_vector_type(4)));
typedef unsigned long long u64;
typedef unsigned int u32;
typedef unsigned short u16;

// ---------------- workspace layout (floats) ----------------
static const size_t OFF_XT   = 0;          // XT2H/XT2L (f16); M aliases after k_knnpq
static const size_t OFF_P    = 4194304;    // P' compact fp32 [b,16,128,256] = 2097152
                                           //  free half [6291456,8388608) holds PKD/PKI
static const size_t OFF_Q    = 8388608;    // Q' fp32 [b,n,256]
static const size_t OFF_SQD  = 12582912;   // 16384
static const size_t OFF_SPFD = 12599296;   // 16384
static const size_t OFF_WSP  = 12746752;   // W f16 splits (131072 floats) + WDP (196608 floats)
static const size_t OFF_FPS  = 13566208;   // 64 (int)
static const size_t OFF_SD   = 13566272;   // 4096

// ---- u64-key top-10 machinery (key = sortable(d)<<32 | idx; keys distinct) ----
__device__ __forceinline__ void insertK(u64 lk[10], u64 k) {
  if (k >= lk[9]) return;
  lk[9] = k;
#pragma unroll
  for (int j = 9; j > 0; j--) {
    u64 a = lk[j-1], b2 = lk[j];
    bool sw = b2 < a;
    lk[j-1] = sw ? b2 : a;
    lk[j]   = sw ? a : b2;
  }
}

#define CASK(a, b) { u64 _x = (a), _y = (b); bool _s = _y < _x; \
  (a) = _s ? _y : _x; (b) = _s ? _x : _y; }

// merge two sorted-asc 10-lists, keep sorted top-10 into lk.
__device__ __forceinline__ void merge10(u64 lk[10], const u64 b[10]) {
  u64 c[10];
#pragma unroll
  for (int i = 0; i < 10; i++) { u64 t = b[9 - i]; u64 a = lk[i]; c[i] = a < t ? a : t; }
  CASK(c[0], c[5]); CASK(c[1], c[6]); CASK(c[2], c[7]); CASK(c[3], c[8]); CASK(c[4], c[9]);
  CASK(c[0], c[1]); CASK(c[1], c[2]); CASK(c[2], c[3]); CASK(c[3], c[4]);
  CASK(c[0], c[1]); CASK(c[1], c[2]); CASK(c[2], c[3]);
  CASK(c[0], c[1]); CASK(c[1], c[2]);
  CASK(c[0], c[1]);
  CASK(c[5], c[6]); CASK(c[6], c[7]); CASK(c[7], c[8]); CASK(c[8], c[9]);
  CASK(c[5], c[6]); CASK(c[6], c[7]); CASK(c[7], c[8]);
  CASK(c[5], c[6]); CASK(c[6], c[7]);
  CASK(c[5], c[6]);
#pragma unroll
  for (int i = 0; i < 10; i++) lk[i] = c[i];
}

// ---------------- K-PRE: fused {fps | sd | split256 | d2s | splitW | wdperm} ----------------
__global__ __launch_bounds__(256) void k_pre(
    const float* __restrict__ df, const float* __restrict__ sf,
    const float* __restrict__ coor, const float* __restrict__ dnW,
    const float* __restrict__ d2sw, const float* __restrict__ d2scb,
    const float* __restrict__ d2sg, const float* __restrict__ d2sbt,
    const float* __restrict__ dsw,
    _Float16* __restrict__ XH, _Float16* __restrict__ XL, float* __restrict__ sqd,
    _Float16* __restrict__ WPh, _Float16* __restrict__ WPl,
    _Float16* __restrict__ WQh, _Float16* __restrict__ WQl,
    float* __restrict__ WDP, float* __restrict__ SD,
    float* __restrict__ spfd, int* __restrict__ fpsidx, float* __restrict__ out2) {
  __shared__ __align__(16) char SMEM[46080];
  const int bid = blockIdx.x;
  const int t = threadIdx.x;

  if (bid < 4) {
    // ---- FPS + out2 gather ----
    int b = bid;
    float (*X)[132] = (float (*)[132])SMEM;
    float* dist = (float*)(SMEM + 16896);
    int* far_s  = (int*)(SMEM + 17024);
    int* sel    = (int*)(SMEM + 17028);
    for (int idx = t; idx < 32 * 32; idx += 256) {
      int r = idx >> 5, q = idx & 31;
      *(float4*)&X[r][q * 4] = *(const float4*)&coor[((size_t)b * 32 + r) * 128 + q * 4];
    }
    if (t < 32) dist[t] = 1e10f;
    if (t == 0) *far_s = 0;
    __syncthreads();
    for (int it = 0; it < 16; it++) {
      int far = *far_s;
      if (t == 0) sel[it] = far;
      if (t < 32) {
        float d = 0.0f;
        for (int c = 0; c < 128; c++) { float dd = X[t][c] - X[far][c]; d = fmaf(dd, dd, d); }
        float dm = dist[t];
        dist[t] = d < dm ? d : dm;
      }
      __syncthreads();
      if (t == 0) {
        float best = -1.0f; int bi = 0;
        for (int m = 0; m < 32; m++) if (dist[m] > best) { best = dist[m]; bi = m; }
        *far_s = bi;
      }
      __syncthreads();
    }
    if (t < 16) fpsidx[b * 16 + t] = sel[t];
    __syncthreads();
    for (int idx = t; idx < 16 * 32; idx += 256) {
      int j = idx >> 5, q = idx & 31;
      *(float4*)&out2[((size_t)b * 16 + j) * 128 + q * 4] = *(const float4*)&X[sel[j]][q * 4];
    }
  } else if (bid < 8) {
    // ---- SD ----
    int b = bid - 4;
    float* Xs = (float*)SMEM;
    for (int k = t; k < 1024; k += 256)
      *(float4*)&Xs[k * 4] = *(const float4*)&sf[(size_t)b * 4096 + k * 4];
    __syncthreads();
#pragma unroll
    for (int rep = 0; rep < 4; rep++) {
      int p = t + rep * 256;
      int s = p >> 5, u = p & 31;
      float acc = 0.0f;
      for (int c = 0; c < 128; c++) {
        float d = Xs[c * 32 + s] - Xs[c * 32 + u];
        acc = fmaf(d, d, acc);
      }
      SD[(size_t)b * 1024 + p] = acc;
    }
  } else if (bid < 264) {
    // ---- split256 ----
    int idx0 = bid - 8;
    int b = idx0 & 3, n0 = (idx0 >> 2) * 64;
    int s0 = n0 >> 7;
    float (*T)[68] = (float (*)[68])SMEM;
    _Float16* Sh = (_Float16*)(SMEM + 34816);
    _Float16* Sl = (_Float16*)(SMEM + 35072);
    {
      int c = t >> 1, nh = (t & 1) * 32;
      const float* src = &df[((size_t)b * 128 + c) * NPNT + n0 + nh];
#pragma unroll
      for (int j = 0; j < 8; j++) *(float4*)&T[c][nh + j * 4] = *(const float4*)&src[j * 4];
    }
    if (t < 128) {
      float x = sf[((size_t)b * 128 + t) * NSTK + s0];
      _Float16 hi = (_Float16)x;
      Sh[t] = hi; Sl[t] = (_Float16)(x - (float)hi);
    }
    __syncthreads();
    {
      int n = t >> 2, cseg = (t & 3) * 32;
      size_t base = ((size_t)b * NPNT + n0 + n) * 256;
      float s = 0.0f;
#pragma unroll
      for (int k = 0; k < 4; k++) {
        half8 hv, lv, shv, slv;
#pragma unroll
        for (int e = 0; e < 8; e++) {
          float x = T[cseg + k * 8 + e][n];
          s = fmaf(x, x, s);
          _Float16 hi = (_Float16)x;
          hv[e] = hi; lv[e] = (_Float16)(x - (float)hi);
          shv[e] = Sh[cseg + k * 8 + e];
          slv[e] = Sl[cseg + k * 8 + e];
        }
        *(half8*)&XH[base + cseg + k * 8] = hv;
        *(half8*)&XL[base + cseg + k * 8] = lv;
        *(half8*)&XH[base + 128 + cseg + k * 8] = shv;
        *(half8*)&XL[base + 128 + cseg + k * 8] = slv;
      }
      s += __shfl_xor(s, 1);
      s += __shfl_xor(s, 2);
      if ((t & 3) == 0) sqd[(size_t)b * NPNT + n0 + n] = s;
    }
  } else if (bid < 520) {
    // ---- d2s ----
    int idx0 = bid - 264;
    int b = idx0 & 3, o0 = ((idx0 >> 2) & 1) * 64, s = idx0 >> 3;
    int n0 = s * 128;
    float (*A)[64]   = (float (*)[64])SMEM;
    float (*Bs)[132] = (float (*)[132])(SMEM + 24576);
    float (*Dr)[17]  = (float (*)[17])(SMEM + 41472);
    float acc[4][8];
#pragma unroll
    for (int i = 0; i < 4; i++)
#pragma unroll
      for (int j = 0; j < 8; j++) acc[i][j] = 0.0f;
    int tn = t & 15, to = t >> 4;
    for (int ic = 0; ic < 128; ic += 32) {
      {
        int ol = t >> 2, q = t & 3;
        const float* src = &d2sw[((size_t)(o0 + ol) * 128 + ic) * 3 + q * 24];
#pragma unroll
        for (int r = 0; r < 6; r++) {
          float4 v = *(const float4*)&src[r * 4];
          int e = q * 24 + r * 4;
          A[e+0][ol] = v.x; A[e+1][ol] = v.y; A[e+2][ol] = v.z; A[e+3][ol] = v.w;
        }
      }
      for (int idx = t; idx < 32 * 33; idx += 256) {
        int row = idx / 33, f4 = idx % 33;
        int nb = n0 + f4 * 4;
        const float* srow = &df[((size_t)b * 128 + ic + row) * NPNT];
        float4 v;
        if (nb + 3 < NPNT) v = *(const float4*)&srow[nb];
        else {
          v.x = srow[nb   < NPNT ? nb   : NPNT-1];
          v.y = srow[nb+1 < NPNT ? nb+1 : NPNT-1];
          v.z = srow[nb+2 < NPNT ? nb+2 : NPNT-1];
          v.w = srow[nb+3 < NPNT ? nb+3 : NPNT-1];
        }
        *(float4*)&Bs[row][f4 * 4] = v;
      }
      __syncthreads();
#pragma unroll 2
      for (int ii = 0; ii < 32; ii++) {
        float bv[12];
        *(float4*)&bv[0] = *(const float4*)&Bs[ii][tn * 8];
        *(float4*)&bv[4] = *(const float4*)&Bs[ii][tn * 8 + 4];
        *(float4*)&bv[8] = *(const float4*)&Bs[ii][tn * 8 + 8];
#pragma unroll
        for (int kw = 0; kw < 3; kw++) {
          float4 av = *(const float4*)&A[ii * 3 + kw][to * 4];
#pragma unroll
          for (int j = 0; j < 8; j++) {
            float bvj = bv[kw + j];
            acc[0][j] = fmaf(av.x, bvj, acc[0][j]);
            acc[1][j] = fmaf(av.y, bvj, acc[1][j]);
            acc[2][j] = fmaf(av.z, bvj, acc[2][j]);
            acc[3][j] = fmaf(av.w, bvj, acc[3][j]);
          }
        }
      }
      __syncthreads();
    }
#pragma unroll
    for (int i = 0; i < 4; i++) {
      int o = o0 + to * 4 + i;
      float gg = d2sg[o], bb = d2scb[o], bo = d2sbt[o];
      float m = 0.0f;
#pragma unroll
      for (int j = 0; j < 8; j++) {
        int p = tn * 8 + j;
        if (p < 126) {
          float v = fmaf(gg, acc[i][j] + bb, bo);
          v = v > 0.0f ? v : 0.0f;
          m = v > m ? v : m;
        }
      }
      Dr[to * 4 + i][tn] = m;
    }
    __syncthreads();
    if (t < 64) {
      float m = 0.0f;
#pragma unroll
      for (int k = 0; k < 16; k++) m = Dr[t][k] > m ? Dr[t][k] : m;
      spfd[((size_t)b * 128 + o0 + t) * NSTK + s] = m;
    }
  } else if (bid < 776) {
    // ---- splitW ----
    int k = bid - 520, o = t;
    float w1 = dnW[(size_t)k * 256 + o];
    float w2 = dnW[(size_t)(k + 256) * 256 + o];
    float p = w1 - w2;
    _Float16 ph = (_Float16)p;  WPh[(size_t)o * 256 + k] = ph;
    WPl[(size_t)o * 256 + k] = (_Float16)(p - (float)ph);
    _Float16 qh = (_Float16)w2; WQh[(size_t)o * 256 + k] = qh;
    WQl[(size_t)o * 256 + k] = (_Float16)(w2 - (float)qh);
  } else {
    // ---- wdperm ----
    int o = bid - 776;
    const float* src = &dsw[(size_t)o * 768];
    float* dst = &WDP[(size_t)o * 768];
#pragma unroll
    for (int kw = 0; kw < 3; kw++)
      dst[kw * 256 + t] = src[t * 3 + kw];
  }
}

// ---------------- K3: sparse mono2 — graph + P/Q + combine, 32 blocks ----------------
__global__ __launch_bounds__(256) void k_sparse_mono2(const float* __restrict__ sf,
    const float* __restrict__ spfd, const int* __restrict__ fps, const float* __restrict__ W,
    const float* __restrict__ g, const float* __restrict__ cb, const float* __restrict__ bt,
    float* __restrict__ out0) {
  int b = blockIdx.x, og = blockIdx.y;
  int t = threadIdx.x;
  __shared__ float X[32][260];
  __shared__ float Qs[32][33];
  __shared__ float Pl[16][33];
  __shared__ float sq[32];
  __shared__ float D[32][33];
  __shared__ int idxs_s[64];
  __shared__ int fps_s[16];
  for (int idx = t; idx < 32 * 256; idx += 256) {
    int n = idx >> 8, c = idx & 255;
    X[n][c] = (c < 128) ? sf[((size_t)b * 128 + c) * NSTK + n]
                        : spfd[((size_t)b * 128 + (c - 128)) * NSTK + n];
  }
  if (t < 16) fps_s[t] = fps[b * 16 + t];
  __syncthreads();
  if (t < 32) {
    float s = 0.0f;
    for (int c = 0; c < 256; c++) s = fmaf(X[t][c], X[t][c], s);
    sq[t] = s;
  }
  __syncthreads();
  {
    int n = t >> 3;
    for (int mg = 0; mg < 4; mg++) {
      int m = (t & 7) + mg * 8;
      float dot = 0.0f;
      for (int c = 0; c < 256; c++) dot = fmaf(X[n][c], X[m][c], dot);
      D[n][m] = (sq[n] - 2.0f * dot) + sq[m];
    }
  }
  __syncthreads();
  if (t < 32) {
    float d0 = 1e30f, d1 = 1e30f; int i0 = 0, i1 = 0;
    for (int m = 0; m < 32; m++) {
      float d = D[t][m];
      if (d < d0) { d1 = d0; i1 = i0; d0 = d; i0 = m; }
      else if (d < d1) { d1 = d; i1 = m; }
    }
    idxs_s[t * 2 + 0] = i0;
    idxs_s[t * 2 + 1] = i1;
  }
  const int ol = t & 31, sg = t >> 5;
  const int o = og * 32 + ol;
  {
    float acc[4] = {0.0f, 0.0f, 0.0f, 0.0f};
    for (int c4 = 0; c4 < 64; c4++) {
      int c = c4 * 4;
      float w0 = W[(size_t)(c + 256) * 256 + o];
      float w1 = W[(size_t)(c + 257) * 256 + o];
      float w2 = W[(size_t)(c + 258) * 256 + o];
      float w3 = W[(size_t)(c + 259) * 256 + o];
#pragma unroll
      for (int k = 0; k < 4; k++) {
        float4 xv = *(const float4*)&X[sg * 4 + k][c];
        acc[k] = fmaf(xv.x, w0, acc[k]);
        acc[k] = fmaf(xv.y, w1, acc[k]);
        acc[k] = fmaf(xv.z, w2, acc[k]);
        acc[k] = fmaf(xv.w, w3, acc[k]);
      }
    }
#pragma unroll
    for (int k = 0; k < 4; k++) Qs[sg * 4 + k][ol] = acc[k];
  }
  if (sg < 4) {
    int fs[4];
#pragma unroll
    for (int k = 0; k < 4; k++) fs[k] = fps_s[sg * 4 + k];
    float acc[4] = {0.0f, 0.0f, 0.0f, 0.0f};
    for (int c4 = 0; c4 < 64; c4++) {
      int c = c4 * 4;
      float p0 = W[(size_t)(c + 0) * 256 + o] - W[(size_t)(c + 256) * 256 + o];
      float p1 = W[(size_t)(c + 1) * 256 + o] - W[(size_t)(c + 257) * 256 + o];
      float p2 = W[(size_t)(c + 2) * 256 + o] - W[(size_t)(c + 258) * 256 + o];
      float p3 = W[(size_t)(c + 3) * 256 + o] - W[(size_t)(c + 259) * 256 + o];
#pragma unroll
      for (int k = 0; k < 4; k++) {
        float4 xv = *(const float4*)&X[fs[k]][c];
        acc[k] = fmaf(xv.x, p0, acc[k]);
        acc[k] = fmaf(xv.y, p1, acc[k]);
        acc[k] = fmaf(xv.z, p2, acc[k]);
        acc[k] = fmaf(xv.w, p3, acc[k]);
      }
    }
#pragma unroll
    for (int k = 0; k < 4; k++) Pl[sg * 4 + k][ol] = acc[k];
  }
  __syncthreads();
  if (t < 32) {
    int oo = og * 32 + t;
    float gg = g[oo], bb = cb[oo], bo = bt[oo];
#pragma unroll
    for (int j = 0; j < 16; j++) {
      int n = fps_s[j];
      int i0 = idxs_s[n * 2 + 0], i1 = idxs_s[n * 2 + 1];
      float p = Pl[j][t];
      float h0 = fmaf(gg, p + Qs[i0][t] + bb, bo); h0 = h0 > 0.0f ? h0 : 0.0f;
      float h1 = fmaf(gg, p + Qs[i1][t] + bb, bo); h1 = h1 > 0.0f ? h1 : 0.0f;
      out0[((size_t)b * 256 + oo) * 16 + j] = h0 > h1 ? h0 : h1;
    }
  }
}

// ---------------- K4+K5 fused: role-split, 2:1 INTERLEAVED dispatch (R13 best) ----------------
#define STAGE(ch2_, p_) { \
  int srow = t >> 2, scol = (t & 3) * 16; \
  size_t gp = (bofs + (size_t)(m0 + (ch2_) * 64 + srow)) * 256 + (p_) * 64 + scol; \
  float4 gh0 = *(const float4*)&XH[gp]; float4 gh1 = *(const float4*)&XH[gp + 8]; \
  float4 gl0 = *(const float4*)&XL[gp]; float4 gl1 = *(const float4*)&XL[gp + 8]; \
  int lo = srow * 72 + scol; \
  *(float4*)&BshH[lo] = gh0; *(float4*)&BshH[lo + 8] = gh1; \
  *(float4*)&BshL[lo] = gl0; *(float4*)&BshL[lo + 8] = gl1; }

#define DWU(wv_, r_, c_) DwU[(((wv_) * 16 + (r_)) * 68) + (c_)]

__global__ __launch_bounds__(256, 4) void k_knnpq(const _Float16* __restrict__ XH,
    const _Float16* __restrict__ XL, const float* __restrict__ sqd, const float* __restrict__ SD,
    const int* __restrict__ fps,
    const _Float16* __restrict__ WPh, const _Float16* __restrict__ WPl,
    const _Float16* __restrict__ WQh, const _Float16* __restrict__ WQl,
    const float* __restrict__ g, const float* __restrict__ cb, const float* __restrict__ bt,
    u32* __restrict__ pkd, u16* __restrict__ pki,
    float* __restrict__ Pc, float* __restrict__ Qp) {
  const int bid0 = blockIdx.x;
  const int t = threadIdx.x;
  const int w = t >> 6, L = t & 63;
  const int c15 = L & 15, q = L >> 4;
  f32x4 zz = {0.0f, 0.0f, 0.0f, 0.0f};

  __shared__ __align__(16) char SMEM[18432];

  const int rrem = bid0 % 3;
  const bool is_knn = (rrem < 2);

  if (is_knn) {
    // ================= knn role ================
    const int bid = (bid0 / 3) * 2 + rrem;   // 0..2047 bijective
    const int h = bid & 15, rb = (bid >> 4) & 31, b = bid >> 9;
    const int jst = rb >> 1;
    const int ph = (rb & 1) * 64;
    const int s_stk = fps[b * 16 + jst];
    const int nsrc = s_stk * 128 + ph + w * 16;
    const int rc0 = rb * 64 + w * 16;
    const size_t bofs = (size_t)b * NPNT;

    _Float16* const BshH = (_Float16*)SMEM;
    _Float16* const BshL = (_Float16*)(SMEM + 64 * 72 * 2);
    unsigned* const DwU = (unsigned*)SMEM;

    half8 ah[4], al[4];
    {
      const _Float16* ap  = XH + (bofs + nsrc + c15) * 256 + q * 8;
      const _Float16* apl = XL + (bofs + nsrc + c15) * 256 + q * 8;
#pragma unroll
      for (int ch = 0; ch < 4; ch++) {
        ah[ch] = *(const half8*)(ap + ch * 32);
        al[ch] = *(const half8*)(apl + ch * 32);
      }
    }
    float snr[4];
#pragma unroll
    for (int r = 0; r < 4; r++) snr[r] = sqd[bofs + nsrc + q * 4 + r];

    u64 lk[10];
#pragma unroll
    for (int j = 0; j < 10; j++) lk[j] = ~0ull;

    const bool own_here = ((s_stk >> 1) == h);
    const int r_sel = L >> 2, sl = L & 3;
    const int u0 = own_here ? s_stk : (h * 2);
    const int u1 = own_here ? (s_stk ^ 1) : (h * 2 + 1);

#pragma unroll 1
    for (int it = 0; it < 2; it++) {
      const int u = (it == 0) ? u0 : u1;
      const int m0 = u * 128;
      const float SDv = SD[((size_t)b * 32 + s_stk) * 32 + u];

#pragma unroll 1
      for (int ch2 = 0; ch2 < 2; ch2++) {
        float smv[4];
#pragma unroll
        for (int cg = 0; cg < 4; cg++) smv[cg] = sqd[bofs + m0 + ch2 * 64 + cg * 16 + c15];

        f32x4 acc[4];
#pragma unroll
        for (int cg = 0; cg < 4; cg++) acc[cg] = zz;

        __syncthreads();
        STAGE(ch2, 0);
        __syncthreads();
#pragma unroll
        for (int chl = 0; chl < 2; chl++) {
#pragma unroll
          for (int cg = 0; cg < 4; cg++) {
            int lo = (cg * 16 + c15) * 72 + chl * 32 + q * 8;
            half8 bh = *(const half8*)&BshH[lo];
            half8 bl = *(const half8*)&BshL[lo];
            acc[cg] = __builtin_amdgcn_mfma_f32_16x16x32_f16(ah[chl], bh, acc[cg], 0, 0, 0);
            acc[cg] = __builtin_amdgcn_mfma_f32_16x16x32_f16(ah[chl], bl, acc[cg], 0, 0, 0);
            acc[cg] = __builtin_amdgcn_mfma_f32_16x16x32_f16(al[chl], bh, acc[cg], 0, 0, 0);
          }
        }
        __syncthreads();
        STAGE(ch2, 1);
        __syncthreads();
#pragma unroll
        for (int chl = 0; chl < 2; chl++) {
#pragma unroll
          for (int cg = 0; cg < 4; cg++) {
            int lo = (cg * 16 + c15) * 72 + chl * 32 + q * 8;
            half8 bh = *(const half8*)&BshH[lo];
            half8 bl = *(const half8*)&BshL[lo];
            acc[cg] = __builtin_amdgcn_mfma_f32_16x16x32_f16(ah[2 + chl], bh, acc[cg], 0, 0, 0);
            acc[cg] = __builtin_amdgcn_mfma_f32_16x16x32_f16(ah[2 + chl], bl, acc[cg], 0, 0, 0);
            acc[cg] = __builtin_amdgcn_mfma_f32_16x16x32_f16(al[2 + chl], bh, acc[cg], 0, 0, 0);
          }
        }
        __syncthreads();

#pragma unroll
        for (int cg = 0; cg < 4; cg++) {
          float basec = SDv + smv[cg];
#pragma unroll
          for (int r = 0; r < 4; r++) {
            float d = fmaf(-2.0f, acc[cg][r], snr[r] + basec);
            unsigned uu = __float_as_uint(d);
            unsigned kk = uu ^ ((unsigned)((int)uu >> 31) | 0x80000000u);
            DWU(w, q * 4 + r, cg * 16 + c15) = kk;
          }
        }
#pragma unroll
        for (int jj = 0; jj < 4; jj++) {
          uint4 kv = *(const uint4*)&DWU(w, r_sel, jj * 16 + sl * 4);
          int ib = m0 + ch2 * 64 + jj * 16 + sl * 4;
          insertK(lk, ((u64)kv.x << 32) | (unsigned)(ib + 0));
          insertK(lk, ((u64)kv.y << 32) | (unsigned)(ib + 1));
          insertK(lk, ((u64)kv.z << 32) | (unsigned)(ib + 2));
          insertK(lk, ((u64)kv.w << 32) | (unsigned)(ib + 3));
        }
      }
    }

#pragma unroll
    for (int m = 1; m <= 2; m <<= 1) {
      u64 o[10];
#pragma unroll
      for (int j = 0; j < 10; j++) o[j] = __shfl_xor(lk[j], m);
      merge10(lk, o);
    }
    if (sl == 0) {
      size_t row = (size_t)b * 2048 + rc0 + r_sel;
      u32* dk = &pkd[(row * 16 + h) * 10];
      u16* di = &pki[(row * 16 + h) * 10];
#pragma unroll
      for (int j = 0; j < 10; j++) {
        dk[j] = (u32)(lk[j] >> 32);
        di[j] = (u16)(lk[j] & 0xffffull);
      }
    }
  } else {
    // ================= pq role ================
    const int bid2 = bid0 / 3;               // 0..1023 bijective
    const int bx = bid2 & 127, by = (bid2 >> 7) & 1, b = bid2 >> 8;
    const int ow = by * 128 + (w >> 1) * 64;
    const size_t bofs = (size_t)b * NPNT;

    {
      const int nw = bx * 32 + (w & 1) * 16;
      f32x4 accQ[4];
#pragma unroll
      for (int cg = 0; cg < 4; cg++) accQ[cg] = zz;
      const _Float16* ap  = XH + (bofs + nw + c15) * 256 + q * 8;
      const _Float16* apl = XL + (bofs + nw + c15) * 256 + q * 8;
#pragma unroll
      for (int ch = 0; ch < 8; ch++) {
        half8 a_h = *(const half8*)(ap + ch * 32);
        half8 a_l = *(const half8*)(apl + ch * 32);
#pragma unroll
        for (int cg = 0; cg < 4; cg++) {
          size_t wb = (size_t)(ow + cg * 16 + c15) * 256 + ch * 32 + q * 8;
          half8 bqh = *(const half8*)(WQh + wb);
          half8 bql = *(const half8*)(WQl + wb);
          accQ[cg] = __builtin_amdgcn_mfma_f32_16x16x32_f16(a_h, bqh, accQ[cg], 0, 0, 0);
          accQ[cg] = __builtin_amdgcn_mfma_f32_16x16x32_f16(a_h, bql, accQ[cg], 0, 0, 0);
          accQ[cg] = __builtin_amdgcn_mfma_f32_16x16x32_f16(a_l, bqh, accQ[cg], 0, 0, 0);
        }
      }
#pragma unroll
      for (int cg = 0; cg < 4; cg++) {
        int o = ow + cg * 16 + c15;
        float gg = g[o];
#pragma unroll
        for (int r = 0; r < 4; r++) {
          Qp[(bofs + nw + q * 4 + r) * 256 + o] = gg * accQ[cg][r];
        }
      }
    }

    if (bx < 64) {
      const int m0 = bx * 32 + (w & 1) * 16;
      const int jst = m0 >> 7;
      const int pbase = m0 & 127;
      const int nsrc = fps[b * 16 + jst] * 128 + pbase;
      f32x4 accP[4];
#pragma unroll
      for (int cg = 0; cg < 4; cg++) accP[cg] = zz;
      const _Float16* ap  = XH + (bofs + nsrc + c15) * 256 + q * 8;
      const _Float16* apl = XL + (bofs + nsrc + c15) * 256 + q * 8;
#pragma unroll
      for (int ch = 0; ch < 8; ch++) {
        half8 a_h = *(const half8*)(ap + ch * 32);
        half8 a_l = *(const half8*)(apl + ch * 32);
#pragma unroll
        for (int cg = 0; cg < 4; cg++) {
          size_t wb = (size_t)(ow + cg * 16 + c15) * 256 + ch * 32 + q * 8;
          half8 bph = *(const half8*)(WPh + wb);
          half8 bpl = *(const half8*)(WPl + wb);
          accP[cg] = __builtin_amdgcn_mfma_f32_16x16x32_f16(a_h, bph, accP[cg], 0, 0, 0);
          accP[cg] = __builtin_amdgcn_mfma_f32_16x16x32_f16(a_h, bpl, accP[cg], 0, 0, 0);
          accP[cg] = __builtin_amdgcn_mfma_f32_16x16x32_f16(a_l, bph, accP[cg], 0, 0, 0);
        }
      }
#pragma unroll
      for (int cg = 0; cg < 4; cg++) {
        int o = ow + cg * 16 + c15;
        float gg = g[o], bb = cb[o], bo = bt[o];
#pragma unroll
        for (int r = 0; r < 4; r++) {
          Pc[(((size_t)b * 16 + jst) * 128 + pbase + q * 4 + r) * 256 + o] =
              fmaf(gg, accP[cg][r] + bb, bo);
        }
      }
    }
  }
}

// ---------------- K6: build M — fused 16-list merge + max-gather ----------------
__global__ __launch_bounds__(256) void k_build_M(const float* __restrict__ Pc, const float* __restrict__ Qp,
    const u32* __restrict__ pkd, const u16* __restrict__ pki, float* __restrict__ M) {
  int pc = blockIdx.x, j = blockIdx.y, b = blockIdx.z;
  int t = threadIdx.x;
  __shared__ int knn_s[16][10];
  {
    int rr = t >> 4, ll = t & 15;
    size_t row = (size_t)b * 2048 + j * 128 + pc * 16 + rr;
    const u32* kd = &pkd[(row * 16 + ll) * 10];
    const u16* ki = &pki[(row * 16 + ll) * 10];
    u64 lk[10];
#pragma unroll
    for (int jj = 0; jj < 10; jj++) lk[jj] = ((u64)kd[jj] << 32) | (u64)ki[jj];
#pragma unroll
    for (int m = 1; m <= 8; m <<= 1) {
      u64 o[10];
#pragma unroll
      for (int jj = 0; jj < 10; jj++) o[jj] = __shfl_xor(lk[jj], m);
      merge10(lk, o);
    }
    if (ll == 0) {
#pragma unroll
      for (int jj = 0; jj < 10; jj++) knn_s[rr][jj] = (int)(lk[jj] & 0xffffull);
    }
  }
  __syncthreads();
#pragma unroll 1
  for (int pi = 0; pi < 16; pi++) {
    size_t m = ((size_t)b * 16 + j) * 128 + pc * 16 + pi;
    float pv = Pc[m * 256 + t];
    float mx = 0.0f;
#pragma unroll
    for (int k = 0; k < 10; k++) {
      float qv = Qp[((size_t)b * NPNT + knn_s[pi][k]) * 256 + t];
      float h = pv + qv;
      mx = h > mx ? h : mx;
    }
    M[m * 256 + t] = mx;
  }
}

// ---------------- K7: downsample GEMM (K-permuted: A=WDP, B=M slices) ----------------
__global__ __launch_bounds__(256) void k_ds_gemm(const float* __restrict__ WDP, const float* __restrict__ M,
    const float* __restrict__ cb, const float* __restrict__ g, const float* __restrict__ bt,
    float* __restrict__ out1) {
  int j = blockIdx.x, o0 = blockIdx.y * 64, b = blockIdx.z;
  int j0 = j * 64;
  int t = threadIdx.x;
  __shared__ float A[32][68];
  __shared__ float Bs[32][68];
  float acc[4][4];
#pragma unroll
  for (int i = 0; i < 4; i++)
#pragma unroll
    for (int jj = 0; jj < 4; jj++) acc[i][jj] = 0.0f;
  int tj = t & 15, to = t >> 4;
  for (int kc = 0; kc < 768; kc += 32) {
    {
      int ol = t >> 2, q = t & 3;
      const float* src = &WDP[(size_t)(o0 + ol) * 768 + kc + q * 8];
      float4 v0 = *(const float4*)src, v1 = *(const float4*)(src + 4);
      int cc = q * 8;
      A[cc+0][ol] = v0.x; A[cc+1][ol] = v0.y; A[cc+2][ol] = v0.z; A[cc+3][ol] = v0.w;
      A[cc+4][ol] = v1.x; A[cc+5][ol] = v1.y; A[cc+6][ol] = v1.z; A[cc+7][ol] = v1.w;
    }
    {
      int jl = t >> 2, q = t & 3;
      int kw = kc >> 8, cbl = (kc & 255) + q * 8;
      int p = 2 * jl - 1 + kw;
      float4 v0, v1;
      if (p >= 0) {
        const float* src = &M[(((size_t)b * 16 + j) * 128 + p) * 256 + cbl];
        v0 = *(const float4*)src; v1 = *(const float4*)(src + 4);
      } else {
        v0.x = v0.y = v0.z = v0.w = 0.0f; v1 = v0;
      }
      int cc = q * 8;
      Bs[cc+0][jl] = v0.x; Bs[cc+1][jl] = v0.y; Bs[cc+2][jl] = v0.z; Bs[cc+3][jl] = v0.w;
      Bs[cc+4][jl] = v1.x; Bs[cc+5][jl] = v1.y; Bs[cc+6][jl] = v1.z; Bs[cc+7][jl] = v1.w;
    }
    __syncthreads();
#pragma unroll 4
    for (int k = 0; k < 32; k++) {
      float4 a = *(const float4*)&A[k][to * 4];
      float4 bv = *(const float4*)&Bs[k][tj * 4];
      float av[4] = {a.x, a.y, a.z, a.w};
      float bb[4] = {bv.x, bv.y, bv.z, bv.w};
#pragma unroll
      for (int i = 0; i < 4; i++)
#pragma unroll
        for (int jj = 0; jj < 4; jj++)
          acc[i][jj] = fmaf(av[i], bb[jj], acc[i][jj]);
    }
    __syncthreads();
  }
#pragma unroll
  for (int i = 0; i < 4; i++) {
    int o = o0 + to * 4 + i;
    float gg = g[o], bb = cb[o], bo = bt[o];
    float4 v;
    float x0 = fmaf(gg, acc[i][0] + bb, bo); v.x = x0 > 0.0f ? x0 : 0.0f;
    float x1 = fmaf(gg, acc[i][1] + bb, bo); v.y = x1 > 0.0f ? x1 : 0.0f;
    float x2 = fmaf(gg, acc[i][2] + bb, bo); v.z = x2 > 0.0f ? x2 : 0.0f;
    float x3 = fmaf(gg, acc[i][3] + bb, bo); v.w = x3 > 0.0f ? x3 : 0.0f;
    *(float4*)&out1[((size_t)b * 256 + o) * 1024 + j0 + tj * 4] = v;
  }
}

extern "C" void kernel_launch(void* const* d_in, const int* in_sizes, int n_in,
                              void* d_out, int out_size, void* d_ws, size_t ws_size,
                              hipStream_t stream) {
  (void)in_sizes; (void)n_in; (void)out_size; (void)ws_size;
  const float* sf    = (const float*)d_in[0];
  const float* df    = (const float*)d_in[1];
  const float* coor  = (const float*)d_in[2];
  const float* d2sw  = (const float*)d_in[3];
  const float* d2sb  = (const float*)d_in[4];
  const float* d2sg  = (const float*)d_in[5];
  const float* d2sbt = (const float*)d_in[6];
  const float* spW   = (const float*)d_in[7];
  const float* spb   = (const float*)d_in[8];
  const float* spg   = (const float*)d_in[9];
  const float* spbt  = (const float*)d_in[10];
  const float* dnW   = (const float*)d_in[11];
  const float* dnb   = (const float*)d_in[12];
  const float* dng   = (const float*)d_in[13];
  const float* dnbt  = (const float*)d_in[14];
  const float* dsw   = (const float*)d_in[15];
  const float* dsb   = (const float*)d_in[16];
  const float* dsg   = (const float*)d_in[17];
  const float* dsbt  = (const float*)d_in[18];

  float* ws   = (float*)d_ws;
  float* Pc   = ws + OFF_P;
  float* Qp   = ws + OFF_Q;
  float* SQD  = ws + OFF_SQD;
  float* SPFD = ws + OFF_SPFD;
  int*   FPS  = (int*)(ws + OFF_FPS);
  float* SD   = ws + OFF_SD;
  _Float16* XT2H = (_Float16*)(ws + OFF_XT);
  _Float16* XT2L = XT2H + (size_t)4 * NPNT * 256;
  float* Mb = ws + OFF_XT;     // M aliases XT region (XT dead after k_knnpq)
  _Float16* WPh = (_Float16*)(ws + OFF_WSP);
  _Float16* WPl = WPh + 65536;
  _Float16* WQh = WPh + 131072;
  _Float16* WQl = WPh + 196608;
  float* WDP = ws + OFF_WSP + 131072;
  u32* PKD = (u32*)(ws + OFF_P + 2097152);
  u16* PKI = (u16*)(ws + OFF_P + 2097152 + 1310720);

  float* out0 = (float*)d_out;
  float* out1 = out0 + 16384;
  float* out2 = out1 + 1048576;

  k_pre<<<dim3(1032), 256, 0, stream>>>(df, sf, coor, dnW, d2sw, d2sb, d2sg, d2sbt, dsw,
                                        XT2H, XT2L, SQD, WPh, WPl, WQh, WQl, WDP, SD,
                                        SPFD, FPS, out2);
  k_sparse_mono2<<<dim3(4, 8), 256, 0, stream>>>(sf, SPFD, FPS, spW, spg, spb, spbt, out0);
  k_knnpq<<<dim3(3072), 256, 0, stream>>>(XT2H, XT2L, SQD, SD, FPS,
                                          WPh, WPl, WQh, WQl, dng, dnb, dnbt,
                                          PKD, PKI, Pc, Qp);
  k_build_M<<<dim3(8, 16, 4), 256, 0, stream>>>(Pc, Qp, PKD, PKI, Mb);
  k_ds_gemm<<<dim3(16, 4, 4), 256, 0, stream>>>(WDP, Mb, dsb, dsg, dsbt, out1);
}

// Round 17
// 371.388 us; speedup vs baseline: 1.2414x; 1.0079x over previous
//
#include <hip/hip_runtime.h>

#define NPNT 4096
#define NSTK 32

typedef _Float16 half8 __attribute__((ext_vector_type(8)));
typedef float f32x4 __attribute__((ext_vector_type(4)));
typedef unsigned long long u64;
typedef unsigned int u32;
typedef unsigned short u16;

// ---------------- workspace layout (floats) ----------------
static const size_t OFF_XT   = 0;          // XT2H/XT2L (f16); M aliases after k_knnpq
static const size_t OFF_P    = 4194304;    // P' compact fp32 [b,16,128,256] = 2097152
                                           //  free half [6291456,8388608) holds PKD/PKI
static const size_t OFF_Q    = 8388608;    // Q' fp32 [b,n,256]
static const size_t OFF_SQD  = 12582912;   // 16384
static const size_t OFF_SPFD = 12599296;   // 16384
static const size_t OFF_WSP  = 12746752;   // W f16 splits (131072 floats) + WDP (196608 floats)
static const size_t OFF_FPS  = 13566208;   // 64 (int)
static const size_t OFF_SD   = 13566272;   // 4096

// ---- u64-key top-10 machinery (key = sortable(d)<<32 | idx; keys distinct) ----
__device__ __forceinline__ void insertK(u64 lk[10], u64 k) {
  if (k >= lk[9]) return;
  lk[9] = k;
#pragma unroll
  for (int j = 9; j > 0; j--) {
    u64 a = lk[j-1], b2 = lk[j];
    bool sw = b2 < a;
    lk[j-1] = sw ? b2 : a;
    lk[j]   = sw ? a : b2;
  }
}

#define CASK(a, b) { u64 _x = (a), _y = (b); bool _s = _y < _x; \
  (a) = _s ? _y : _x; (b) = _s ? _x : _y; }

// merge two sorted-asc 10-lists, keep sorted top-10 into lk.
__device__ __forceinline__ void merge10(u64 lk[10], const u64 b[10]) {
  u64 c[10];
#pragma unroll
  for (int i = 0; i < 10; i++) { u64 t = b[9 - i]; u64 a = lk[i]; c[i] = a < t ? a : t; }
  CASK(c[0], c[5]); CASK(c[1], c[6]); CASK(c[2], c[7]); CASK(c[3], c[8]); CASK(c[4], c[9]);
  CASK(c[0], c[1]); CASK(c[1], c[2]); CASK(c[2], c[3]); CASK(c[3], c[4]);
  CASK(c[0], c[1]); CASK(c[1], c[2]); CASK(c[2], c[3]);
  CASK(c[0], c[1]); CASK(c[1], c[2]);
  CASK(c[0], c[1]);
  CASK(c[5], c[6]); CASK(c[6], c[7]); CASK(c[7], c[8]); CASK(c[8], c[9]);
  CASK(c[5], c[6]); CASK(c[6], c[7]); CASK(c[7], c[8]);
  CASK(c[5], c[6]); CASK(c[6], c[7]);
  CASK(c[5], c[6]);
#pragma unroll
  for (int i = 0; i < 10; i++) lk[i] = c[i];
}

// ---------------- K-PRE: fused {fps | sd | split256 | d2s | splitW | wdperm} ----------------
__global__ __launch_bounds__(256) void k_pre(
    const float* __restrict__ df, const float* __restrict__ sf,
    const float* __restrict__ coor, const float* __restrict__ dnW,
    const float* __restrict__ d2sw, const float* __restrict__ d2scb,
    const float* __restrict__ d2sg, const float* __restrict__ d2sbt,
    const float* __restrict__ dsw,
    _Float16* __restrict__ XH, _Float16* __restrict__ XL, float* __restrict__ sqd,
    _Float16* __restrict__ WPh, _Float16* __restrict__ WPl,
    _Float16* __restrict__ WQh, _Float16* __restrict__ WQl,
    float* __restrict__ WDP, float* __restrict__ SD,
    float* __restrict__ spfd, int* __restrict__ fpsidx, float* __restrict__ out2) {
  __shared__ __align__(16) char SMEM[46080];
  const int bid = blockIdx.x;
  const int t = threadIdx.x;

  if (bid < 4) {
    // ---- FPS + out2 gather ----
    int b = bid;
    float (*X)[132] = (float (*)[132])SMEM;
    float* dist = (float*)(SMEM + 16896);
    int* far_s  = (int*)(SMEM + 17024);
    int* sel    = (int*)(SMEM + 17028);
    for (int idx = t; idx < 32 * 32; idx += 256) {
      int r = idx >> 5, q = idx & 31;
      *(float4*)&X[r][q * 4] = *(const float4*)&coor[((size_t)b * 32 + r) * 128 + q * 4];
    }
    if (t < 32) dist[t] = 1e10f;
    if (t == 0) *far_s = 0;
    __syncthreads();
    for (int it = 0; it < 16; it++) {
      int far = *far_s;
      if (t == 0) sel[it] = far;
      if (t < 32) {
        float d = 0.0f;
        for (int c = 0; c < 128; c++) { float dd = X[t][c] - X[far][c]; d = fmaf(dd, dd, d); }
        float dm = dist[t];
        dist[t] = d < dm ? d : dm;
      }
      __syncthreads();
      if (t == 0) {
        float best = -1.0f; int bi = 0;
        for (int m = 0; m < 32; m++) if (dist[m] > best) { best = dist[m]; bi = m; }
        *far_s = bi;
      }
      __syncthreads();
    }
    if (t < 16) fpsidx[b * 16 + t] = sel[t];
    __syncthreads();
    for (int idx = t; idx < 16 * 32; idx += 256) {
      int j = idx >> 5, q = idx & 31;
      *(float4*)&out2[((size_t)b * 16 + j) * 128 + q * 4] = *(const float4*)&X[sel[j]][q * 4];
    }
  } else if (bid < 8) {
    // ---- SD ----
    int b = bid - 4;
    float* Xs = (float*)SMEM;
    for (int k = t; k < 1024; k += 256)
      *(float4*)&Xs[k * 4] = *(const float4*)&sf[(size_t)b * 4096 + k * 4];
    __syncthreads();
#pragma unroll
    for (int rep = 0; rep < 4; rep++) {
      int p = t + rep * 256;
      int s = p >> 5, u = p & 31;
      float acc = 0.0f;
      for (int c = 0; c < 128; c++) {
        float d = Xs[c * 32 + s] - Xs[c * 32 + u];
        acc = fmaf(d, d, acc);
      }
      SD[(size_t)b * 1024 + p] = acc;
    }
  } else if (bid < 264) {
    // ---- split256 ----
    int idx0 = bid - 8;
    int b = idx0 & 3, n0 = (idx0 >> 2) * 64;
    int s0 = n0 >> 7;
    float (*T)[68] = (float (*)[68])SMEM;
    _Float16* Sh = (_Float16*)(SMEM + 34816);
    _Float16* Sl = (_Float16*)(SMEM + 35072);
    {
      int c = t >> 1, nh = (t & 1) * 32;
      const float* src = &df[((size_t)b * 128 + c) * NPNT + n0 + nh];
#pragma unroll
      for (int j = 0; j < 8; j++) *(float4*)&T[c][nh + j * 4] = *(const float4*)&src[j * 4];
    }
    if (t < 128) {
      float x = sf[((size_t)b * 128 + t) * NSTK + s0];
      _Float16 hi = (_Float16)x;
      Sh[t] = hi; Sl[t] = (_Float16)(x - (float)hi);
    }
    __syncthreads();
    {
      int n = t >> 2, cseg = (t & 3) * 32;
      size_t base = ((size_t)b * NPNT + n0 + n) * 256;
      float s = 0.0f;
#pragma unroll
      for (int k = 0; k < 4; k++) {
        half8 hv, lv, shv, slv;
#pragma unroll
        for (int e = 0; e < 8; e++) {
          float x = T[cseg + k * 8 + e][n];
          s = fmaf(x, x, s);
          _Float16 hi = (_Float16)x;
          hv[e] = hi; lv[e] = (_Float16)(x - (float)hi);
          shv[e] = Sh[cseg + k * 8 + e];
          slv[e] = Sl[cseg + k * 8 + e];
        }
        *(half8*)&XH[base + cseg + k * 8] = hv;
        *(half8*)&XL[base + cseg + k * 8] = lv;
        *(half8*)&XH[base + 128 + cseg + k * 8] = shv;
        *(half8*)&XL[base + 128 + cseg + k * 8] = slv;
      }
      s += __shfl_xor(s, 1);
      s += __shfl_xor(s, 2);
      if ((t & 3) == 0) sqd[(size_t)b * NPNT + n0 + n] = s;
    }
  } else if (bid < 520) {
    // ---- d2s ----
    int idx0 = bid - 264;
    int b = idx0 & 3, o0 = ((idx0 >> 2) & 1) * 64, s = idx0 >> 3;
    int n0 = s * 128;
    float (*A)[64]   = (float (*)[64])SMEM;
    float (*Bs)[132] = (float (*)[132])(SMEM + 24576);
    float (*Dr)[17]  = (float (*)[17])(SMEM + 41472);
    float acc[4][8];
#pragma unroll
    for (int i = 0; i < 4; i++)
#pragma unroll
      for (int j = 0; j < 8; j++) acc[i][j] = 0.0f;
    int tn = t & 15, to = t >> 4;
    for (int ic = 0; ic < 128; ic += 32) {
      {
        int ol = t >> 2, q = t & 3;
        const float* src = &d2sw[((size_t)(o0 + ol) * 128 + ic) * 3 + q * 24];
#pragma unroll
        for (int r = 0; r < 6; r++) {
          float4 v = *(const float4*)&src[r * 4];
          int e = q * 24 + r * 4;
          A[e+0][ol] = v.x; A[e+1][ol] = v.y; A[e+2][ol] = v.z; A[e+3][ol] = v.w;
        }
      }
      for (int idx = t; idx < 32 * 33; idx += 256) {
        int row = idx / 33, f4 = idx % 33;
        int nb = n0 + f4 * 4;
        const float* srow = &df[((size_t)b * 128 + ic + row) * NPNT];
        float4 v;
        if (nb + 3 < NPNT) v = *(const float4*)&srow[nb];
        else {
          v.x = srow[nb   < NPNT ? nb   : NPNT-1];
          v.y = srow[nb+1 < NPNT ? nb+1 : NPNT-1];
          v.z = srow[nb+2 < NPNT ? nb+2 : NPNT-1];
          v.w = srow[nb+3 < NPNT ? nb+3 : NPNT-1];
        }
        *(float4*)&Bs[row][f4 * 4] = v;
      }
      __syncthreads();
#pragma unroll 2
      for (int ii = 0; ii < 32; ii++) {
        float bv[12];
        *(float4*)&bv[0] = *(const float4*)&Bs[ii][tn * 8];
        *(float4*)&bv[4] = *(const float4*)&Bs[ii][tn * 8 + 4];
        *(float4*)&bv[8] = *(const float4*)&Bs[ii][tn * 8 + 8];
#pragma unroll
        for (int kw = 0; kw < 3; kw++) {
          float4 av = *(const float4*)&A[ii * 3 + kw][to * 4];
#pragma unroll
          for (int j = 0; j < 8; j++) {
            float bvj = bv[kw + j];
            acc[0][j] = fmaf(av.x, bvj, acc[0][j]);
            acc[1][j] = fmaf(av.y, bvj, acc[1][j]);
            acc[2][j] = fmaf(av.z, bvj, acc[2][j]);
            acc[3][j] = fmaf(av.w, bvj, acc[3][j]);
          }
        }
      }
      __syncthreads();
    }
#pragma unroll
    for (int i = 0; i < 4; i++) {
      int o = o0 + to * 4 + i;
      float gg = d2sg[o], bb = d2scb[o], bo = d2sbt[o];
      float m = 0.0f;
#pragma unroll
      for (int j = 0; j < 8; j++) {
        int p = tn * 8 + j;
        if (p < 126) {
          float v = fmaf(gg, acc[i][j] + bb, bo);
          v = v > 0.0f ? v : 0.0f;
          m = v > m ? v : m;
        }
      }
      Dr[to * 4 + i][tn] = m;
    }
    __syncthreads();
    if (t < 64) {
      float m = 0.0f;
#pragma unroll
      for (int k = 0; k < 16; k++) m = Dr[t][k] > m ? Dr[t][k] : m;
      spfd[((size_t)b * 128 + o0 + t) * NSTK + s] = m;
    }
  } else if (bid < 776) {
    // ---- splitW ----
    int k = bid - 520, o = t;
    float w1 = dnW[(size_t)k * 256 + o];
    float w2 = dnW[(size_t)(k + 256) * 256 + o];
    float p = w1 - w2;
    _Float16 ph = (_Float16)p;  WPh[(size_t)o * 256 + k] = ph;
    WPl[(size_t)o * 256 + k] = (_Float16)(p - (float)ph);
    _Float16 qh = (_Float16)w2; WQh[(size_t)o * 256 + k] = qh;
    WQl[(size_t)o * 256 + k] = (_Float16)(w2 - (float)qh);
  } else {
    // ---- wdperm ----
    int o = bid - 776;
    const float* src = &dsw[(size_t)o * 768];
    float* dst = &WDP[(size_t)o * 768];
#pragma unroll
    for (int kw = 0; kw < 3; kw++)
      dst[kw * 256 + t] = src[t * 3 + kw];
  }
}

// ---------------- K3: sparse mono2 — graph + P/Q + combine, 32 blocks ----------------
__global__ __launch_bounds__(256) void k_sparse_mono2(const float* __restrict__ sf,
    const float* __restrict__ spfd, const int* __restrict__ fps, const float* __restrict__ W,
    const float* __restrict__ g, const float* __restrict__ cb, const float* __restrict__ bt,
    float* __restrict__ out0) {
  int b = blockIdx.x, og = blockIdx.y;
  int t = threadIdx.x;
  __shared__ float X[32][260];
  __shared__ float Qs[32][33];
  __shared__ float Pl[16][33];
  __shared__ float sq[32];
  __shared__ float D[32][33];
  __shared__ int idxs_s[64];
  __shared__ int fps_s[16];
  for (int idx = t; idx < 32 * 256; idx += 256) {
    int n = idx >> 8, c = idx & 255;
    X[n][c] = (c < 128) ? sf[((size_t)b * 128 + c) * NSTK + n]
                        : spfd[((size_t)b * 128 + (c - 128)) * NSTK + n];
  }
  if (t < 16) fps_s[t] = fps[b * 16 + t];
  __syncthreads();
  if (t < 32) {
    float s = 0.0f;
    for (int c = 0; c < 256; c++) s = fmaf(X[t][c], X[t][c], s);
    sq[t] = s;
  }
  __syncthreads();
  {
    int n = t >> 3;
    for (int mg = 0; mg < 4; mg++) {
      int m = (t & 7) + mg * 8;
      float dot = 0.0f;
      for (int c = 0; c < 256; c++) dot = fmaf(X[n][c], X[m][c], dot);
      D[n][m] = (sq[n] - 2.0f * dot) + sq[m];
    }
  }
  __syncthreads();
  if (t < 32) {
    float d0 = 1e30f, d1 = 1e30f; int i0 = 0, i1 = 0;
    for (int m = 0; m < 32; m++) {
      float d = D[t][m];
      if (d < d0) { d1 = d0; i1 = i0; d0 = d; i0 = m; }
      else if (d < d1) { d1 = d; i1 = m; }
    }
    idxs_s[t * 2 + 0] = i0;
    idxs_s[t * 2 + 1] = i1;
  }
  const int ol = t & 31, sg = t >> 5;
  const int o = og * 32 + ol;
  {
    float acc[4] = {0.0f, 0.0f, 0.0f, 0.0f};
    for (int c4 = 0; c4 < 64; c4++) {
      int c = c4 * 4;
      float w0 = W[(size_t)(c + 256) * 256 + o];
      float w1 = W[(size_t)(c + 257) * 256 + o];
      float w2 = W[(size_t)(c + 258) * 256 + o];
      float w3 = W[(size_t)(c + 259) * 256 + o];
#pragma unroll
      for (int k = 0; k < 4; k++) {
        float4 xv = *(const float4*)&X[sg * 4 + k][c];
        acc[k] = fmaf(xv.x, w0, acc[k]);
        acc[k] = fmaf(xv.y, w1, acc[k]);
        acc[k] = fmaf(xv.z, w2, acc[k]);
        acc[k] = fmaf(xv.w, w3, acc[k]);
      }
    }
#pragma unroll
    for (int k = 0; k < 4; k++) Qs[sg * 4 + k][ol] = acc[k];
  }
  if (sg < 4) {
    int fs[4];
#pragma unroll
    for (int k = 0; k < 4; k++) fs[k] = fps_s[sg * 4 + k];
    float acc[4] = {0.0f, 0.0f, 0.0f, 0.0f};
    for (int c4 = 0; c4 < 64; c4++) {
      int c = c4 * 4;
      float p0 = W[(size_t)(c + 0) * 256 + o] - W[(size_t)(c + 256) * 256 + o];
      float p1 = W[(size_t)(c + 1) * 256 + o] - W[(size_t)(c + 257) * 256 + o];
      float p2 = W[(size_t)(c + 2) * 256 + o] - W[(size_t)(c + 258) * 256 + o];
      float p3 = W[(size_t)(c + 3) * 256 + o] - W[(size_t)(c + 259) * 256 + o];
#pragma unroll
      for (int k = 0; k < 4; k++) {
        float4 xv = *(const float4*)&X[fs[k]][c];
        acc[k] = fmaf(xv.x, p0, acc[k]);
        acc[k] = fmaf(xv.y, p1, acc[k]);
        acc[k] = fmaf(xv.z, p2, acc[k]);
        acc[k] = fmaf(xv.w, p3, acc[k]);
      }
    }
#pragma unroll
    for (int k = 0; k < 4; k++) Pl[sg * 4 + k][ol] = acc[k];
  }
  __syncthreads();
  if (t < 32) {
    int oo = og * 32 + t;
    float gg = g[oo], bb = cb[oo], bo = bt[oo];
#pragma unroll
    for (int j = 0; j < 16; j++) {
      int n = fps_s[j];
      int i0 = idxs_s[n * 2 + 0], i1 = idxs_s[n * 2 + 1];
      float p = Pl[j][t];
      float h0 = fmaf(gg, p + Qs[i0][t] + bb, bo); h0 = h0 > 0.0f ? h0 : 0.0f;
      float h1 = fmaf(gg, p + Qs[i1][t] + bb, bo); h1 = h1 > 0.0f ? h1 : 0.0f;
      out0[((size_t)b * 256 + oo) * 16 + j] = h0 > h1 ? h0 : h1;
    }
  }
}

// ---------------- K4+K5 fused: role-split, 2:1 INTERLEAVED dispatch (R13 best) ----------------
#define STAGE(ch2_, p_) { \
  int srow = t >> 2, scol = (t & 3) * 16; \
  size_t gp = (bofs + (size_t)(m0 + (ch2_) * 64 + srow)) * 256 + (p_) * 64 + scol; \
  float4 gh0 = *(const float4*)&XH[gp]; float4 gh1 = *(const float4*)&XH[gp + 8]; \
  float4 gl0 = *(const float4*)&XL[gp]; float4 gl1 = *(const float4*)&XL[gp + 8]; \
  int lo = srow * 72 + scol; \
  *(float4*)&BshH[lo] = gh0; *(float4*)&BshH[lo + 8] = gh1; \
  *(float4*)&BshL[lo] = gl0; *(float4*)&BshL[lo + 8] = gl1; }

#define DWU(wv_, r_, c_) DwU[(((wv_) * 16 + (r_)) * 68) + (c_)]

__global__ __launch_bounds__(256, 4) void k_knnpq(const _Float16* __restrict__ XH,
    const _Float16* __restrict__ XL, const float* __restrict__ sqd, const float* __restrict__ SD,
    const int* __restrict__ fps,
    const _Float16* __restrict__ WPh, const _Float16* __restrict__ WPl,
    const _Float16* __restrict__ WQh, const _Float16* __restrict__ WQl,
    const float* __restrict__ g, const float* __restrict__ cb, const float* __restrict__ bt,
    u32* __restrict__ pkd, u16* __restrict__ pki,
    float* __restrict__ Pc, float* __restrict__ Qp) {
  const int bid0 = blockIdx.x;
  const int t = threadIdx.x;
  const int w = t >> 6, L = t & 63;
  const int c15 = L & 15, q = L >> 4;
  f32x4 zz = {0.0f, 0.0f, 0.0f, 0.0f};

  __shared__ __align__(16) char SMEM[18432];

  const int rrem = bid0 % 3;
  const bool is_knn = (rrem < 2);

  if (is_knn) {
    // ================= knn role ================
    const int bid = (bid0 / 3) * 2 + rrem;   // 0..2047 bijective
    const int h = bid & 15, rb = (bid >> 4) & 31, b = bid >> 9;
    const int jst = rb >> 1;
    const int ph = (rb & 1) * 64;
    const int s_stk = fps[b * 16 + jst];
    const int nsrc = s_stk * 128 + ph + w * 16;
    const int rc0 = rb * 64 + w * 16;
    const size_t bofs = (size_t)b * NPNT;

    _Float16* const BshH = (_Float16*)SMEM;
    _Float16* const BshL = (_Float16*)(SMEM + 64 * 72 * 2);
    unsigned* const DwU = (unsigned*)SMEM;

    half8 ah[4], al[4];
    {
      const _Float16* ap  = XH + (bofs + nsrc + c15) * 256 + q * 8;
      const _Float16* apl = XL + (bofs + nsrc + c15) * 256 + q * 8;
#pragma unroll
      for (int ch = 0; ch < 4; ch++) {
        ah[ch] = *(const half8*)(ap + ch * 32);
        al[ch] = *(const half8*)(apl + ch * 32);
      }
    }
    float snr[4];
#pragma unroll
    for (int r = 0; r < 4; r++) snr[r] = sqd[bofs + nsrc + q * 4 + r];

    u64 lk[10];
#pragma unroll
    for (int j = 0; j < 10; j++) lk[j] = ~0ull;

    const bool own_here = ((s_stk >> 1) == h);
    const int r_sel = L >> 2, sl = L & 3;
    const int u0 = own_here ? s_stk : (h * 2);
    const int u1 = own_here ? (s_stk ^ 1) : (h * 2 + 1);

#pragma unroll 1
    for (int it = 0; it < 2; it++) {
      const int u = (it == 0) ? u0 : u1;
      const int m0 = u * 128;
      const float SDv = SD[((size_t)b * 32 + s_stk) * 32 + u];

#pragma unroll 1
      for (int ch2 = 0; ch2 < 2; ch2++) {
        float smv[4];
#pragma unroll
        for (int cg = 0; cg < 4; cg++) smv[cg] = sqd[bofs + m0 + ch2 * 64 + cg * 16 + c15];

        f32x4 acc[4];
#pragma unroll
        for (int cg = 0; cg < 4; cg++) acc[cg] = zz;

        __syncthreads();
        STAGE(ch2, 0);
        __syncthreads();
#pragma unroll
        for (int chl = 0; chl < 2; chl++) {
#pragma unroll
          for (int cg = 0; cg < 4; cg++) {
            int lo = (cg * 16 + c15) * 72 + chl * 32 + q * 8;
            half8 bh = *(const half8*)&BshH[lo];
            half8 bl = *(const half8*)&BshL[lo];
            acc[cg] = __builtin_amdgcn_mfma_f32_16x16x32_f16(ah[chl], bh, acc[cg], 0, 0, 0);
            acc[cg] = __builtin_amdgcn_mfma_f32_16x16x32_f16(ah[chl], bl, acc[cg], 0, 0, 0);
            acc[cg] = __builtin_amdgcn_mfma_f32_16x16x32_f16(al[chl], bh, acc[cg], 0, 0, 0);
          }
        }
        __syncthreads();
        STAGE(ch2, 1);
        __syncthreads();
#pragma unroll
        for (int chl = 0; chl < 2; chl++) {
#pragma unroll
          for (int cg = 0; cg < 4; cg++) {
            int lo = (cg * 16 + c15) * 72 + chl * 32 + q * 8;
            half8 bh = *(const half8*)&BshH[lo];
            half8 bl = *(const half8*)&BshL[lo];
            acc[cg] = __builtin_amdgcn_mfma_f32_16x16x32_f16(ah[2 + chl], bh, acc[cg], 0, 0, 0);
            acc[cg] = __builtin_amdgcn_mfma_f32_16x16x32_f16(ah[2 + chl], bl, acc[cg], 0, 0, 0);
            acc[cg] = __builtin_amdgcn_mfma_f32_16x16x32_f16(al[2 + chl], bh, acc[cg], 0, 0, 0);
          }
        }
        __syncthreads();

#pragma unroll
        for (int cg = 0; cg < 4; cg++) {
          float basec = SDv + smv[cg];
#pragma unroll
          for (int r = 0; r < 4; r++) {
            float d = fmaf(-2.0f, acc[cg][r], snr[r] + basec);
            unsigned uu = __float_as_uint(d);
            unsigned kk = uu ^ ((unsigned)((int)uu >> 31) | 0x80000000u);
            DWU(w, q * 4 + r, cg * 16 + c15) = kk;
          }
        }
#pragma unroll
        for (int jj = 0; jj < 4; jj++) {
          uint4 kv = *(const uint4*)&DWU(w, r_sel, jj * 16 + sl * 4);
          int ib = m0 + ch2 * 64 + jj * 16 + sl * 4;
          insertK(lk, ((u64)kv.x << 32) | (unsigned)(ib + 0));
          insertK(lk, ((u64)kv.y << 32) | (unsigned)(ib + 1));
          insertK(lk, ((u64)kv.z << 32) | (unsigned)(ib + 2));
          insertK(lk, ((u64)kv.w << 32) | (unsigned)(ib + 3));
        }
      }
    }

#pragma unroll
    for (int m = 1; m <= 2; m <<= 1) {
      u64 o[10];
#pragma unroll
      for (int j = 0; j < 10; j++) o[j] = __shfl_xor(lk[j], m);
      merge10(lk, o);
    }
    if (sl == 0) {
      size_t row = (size_t)b * 2048 + rc0 + r_sel;
      u32* dk = &pkd[(row * 16 + h) * 10];
      u16* di = &pki[(row * 16 + h) * 10];
#pragma unroll
      for (int j = 0; j < 10; j++) {
        dk[j] = (u32)(lk[j] >> 32);
        di[j] = (u16)(lk[j] & 0xffffull);
      }
    }
  } else {
    // ================= pq role ================
    const int bid2 = bid0 / 3;               // 0..1023 bijective
    const int bx = bid2 & 127, by = (bid2 >> 7) & 1, b = bid2 >> 8;
    const int ow = by * 128 + (w >> 1) * 64;
    const size_t bofs = (size_t)b * NPNT;

    {
      const int nw = bx * 32 + (w & 1) * 16;
      f32x4 accQ[4];
#pragma unroll
      for (int cg = 0; cg < 4; cg++) accQ[cg] = zz;
      const _Float16* ap  = XH + (bofs + nw + c15) * 256 + q * 8;
      const _Float16* apl = XL + (bofs + nw + c15) * 256 + q * 8;
#pragma unroll
      for (int ch = 0; ch < 8; ch++) {
        half8 a_h = *(const half8*)(ap + ch * 32);
        half8 a_l = *(const half8*)(apl + ch * 32);
#pragma unroll
        for (int cg = 0; cg < 4; cg++) {
          size_t wb = (size_t)(ow + cg * 16 + c15) * 256 + ch * 32 + q * 8;
          half8 bqh = *(const half8*)(WQh + wb);
          half8 bql = *(const half8*)(WQl + wb);
          accQ[cg] = __builtin_amdgcn_mfma_f32_16x16x32_f16(a_h, bqh, accQ[cg], 0, 0, 0);
          accQ[cg] = __builtin_amdgcn_mfma_f32_16x16x32_f16(a_h, bql, accQ[cg], 0, 0, 0);
          accQ[cg] = __builtin_amdgcn_mfma_f32_16x16x32_f16(a_l, bqh, accQ[cg], 0, 0, 0);
        }
      }
#pragma unroll
      for (int cg = 0; cg < 4; cg++) {
        int o = ow + cg * 16 + c15;
        float gg = g[o];
#pragma unroll
        for (int r = 0; r < 4; r++) {
          Qp[(bofs + nw + q * 4 + r) * 256 + o] = gg * accQ[cg][r];
        }
      }
    }

    if (bx < 64) {
      const int m0 = bx * 32 + (w & 1) * 16;
      const int jst = m0 >> 7;
      const int pbase = m0 & 127;
      const int nsrc = fps[b * 16 + jst] * 128 + pbase;
      f32x4 accP[4];
#pragma unroll
      for (int cg = 0; cg < 4; cg++) accP[cg] = zz;
      const _Float16* ap  = XH + (bofs + nsrc + c15) * 256 + q * 8;
      const _Float16* apl = XL + (bofs + nsrc + c15) * 256 + q * 8;
#pragma unroll
      for (int ch = 0; ch < 8; ch++) {
        half8 a_h = *(const half8*)(ap + ch * 32);
        half8 a_l = *(const half8*)(apl + ch * 32);
#pragma unroll
        for (int cg = 0; cg < 4; cg++) {
          size_t wb = (size_t)(ow + cg * 16 + c15) * 256 + ch * 32 + q * 8;
          half8 bph = *(const half8*)(WPh + wb);
          half8 bpl = *(const half8*)(WPl + wb);
          accP[cg] = __builtin_amdgcn_mfma_f32_16x16x32_f16(a_h, bph, accP[cg], 0, 0, 0);
          accP[cg] = __builtin_amdgcn_mfma_f32_16x16x32_f16(a_h, bpl, accP[cg], 0, 0, 0);
          accP[cg] = __builtin_amdgcn_mfma_f32_16x16x32_f16(a_l, bph, accP[cg], 0, 0, 0);
        }
      }
#pragma unroll
      for (int cg = 0; cg < 4; cg++) {
        int o = ow + cg * 16 + c15;
        float gg = g[o], bb = cb[o], bo = bt[o];
#pragma unroll
        for (int r = 0; r < 4; r++) {
          Pc[(((size_t)b * 16 + jst) * 128 + pbase + q * 4 + r) * 256 + o] =
              fmaf(gg, accP[cg][r] + bb, bo);
        }
      }
    }
  }
}

// ---------------- K6: build M — fused 16-list merge + max-gather ----------------
__global__ __launch_bounds__(256) void k_build_M(const float* __restrict__ Pc, const float* __restrict__ Qp,
    const u32* __restrict__ pkd, const u16* __restrict__ pki, float* __restrict__ M) {
  int pc = blockIdx.x, j = blockIdx.y, b = blockIdx.z;
  int t = threadIdx.x;
  __shared__ int knn_s[16][10];
  {
    int rr = t >> 4, ll = t & 15;
    size_t row = (size_t)b * 2048 + j * 128 + pc * 16 + rr;
    const u32* kd = &pkd[(row * 16 + ll) * 10];
    const u16* ki = &pki[(row * 16 + ll) * 10];
    u64 lk[10];
#pragma unroll
    for (int jj = 0; jj < 10; jj++) lk[jj] = ((u64)kd[jj] << 32) | (u64)ki[jj];
#pragma unroll
    for (int m = 1; m <= 8; m <<= 1) {
      u64 o[10];
#pragma unroll
      for (int jj = 0; jj < 10; jj++) o[jj] = __shfl_xor(lk[jj], m);
      merge10(lk, o);
    }
    if (ll == 0) {
#pragma unroll
      for (int jj = 0; jj < 10; jj++) knn_s[rr][jj] = (int)(lk[jj] & 0xffffull);
    }
  }
  __syncthreads();
#pragma unroll 1
  for (int pi = 0; pi < 16; pi++) {
    size_t m = ((size_t)b * 16 + j) * 128 + pc * 16 + pi;
    float pv = Pc[m * 256 + t];
    float mx = 0.0f;
#pragma unroll
    for (int k = 0; k < 10; k++) {
      float qv = Qp[((size_t)b * NPNT + knn_s[pi][k]) * 256 + t];
      float h = pv + qv;
      mx = h > mx ? h : mx;
    }
    M[m * 256 + t] = mx;
  }
}

// ---------------- K7: downsample GEMM — R17: 2 blocks/CU via j-tile 64->32 ----------------
// grid (32,4,4)=512 blocks; stroke = jb>>1, pp = (jb&1)*32 + jl. acc[2][4] (fewer regs).
__global__ __launch_bounds__(256) void k_ds_gemm(const float* __restrict__ WDP, const float* __restrict__ M,
    const float* __restrict__ cb, const float* __restrict__ g, const float* __restrict__ bt,
    float* __restrict__ out1) {
  int jb = blockIdx.x, o0 = blockIdx.y * 64, b = blockIdx.z;
  int sj = jb >> 1;             // stroke 0..15
  int pp0 = (jb & 1) * 32;      // pp offset within stroke
  int t = threadIdx.x;
  __shared__ float A[32][68];
  __shared__ float Bs[32][36];
  float acc[2][4];
#pragma unroll
  for (int i = 0; i < 2; i++)
#pragma unroll
    for (int jj = 0; jj < 4; jj++) acc[i][jj] = 0.0f;
  int tj = t & 7, to = t >> 3;  // tj: j-quad (8x4=32 j), to: o-pair (32x2=64 o)
  for (int kc = 0; kc < 768; kc += 32) {
    {
      int ol = t >> 2, q = t & 3;
      const float* src = &WDP[(size_t)(o0 + ol) * 768 + kc + q * 8];
      float4 v0 = *(const float4*)src, v1 = *(const float4*)(src + 4);
      int cc = q * 8;
      A[cc+0][ol] = v0.x; A[cc+1][ol] = v0.y; A[cc+2][ol] = v0.z; A[cc+3][ol] = v0.w;
      A[cc+4][ol] = v1.x; A[cc+5][ol] = v1.y; A[cc+6][ol] = v1.z; A[cc+7][ol] = v1.w;
    }
    {
      int jl = t >> 3, q = t & 7;     // jl = local pp (0..31), q: col quad (8x4=32 kc)
      int kw = kc >> 8, cbl = (kc & 255) + q * 4;
      int p = 2 * (pp0 + jl) - 1 + kw;   // in [-1, 127]
      float4 v0;
      if (p >= 0) {
        v0 = *(const float4*)&M[(((size_t)b * 16 + sj) * 128 + p) * 256 + cbl];
      } else {
        v0.x = v0.y = v0.z = v0.w = 0.0f;
      }
      int cc = q * 4;
      Bs[cc+0][jl] = v0.x; Bs[cc+1][jl] = v0.y; Bs[cc+2][jl] = v0.z; Bs[cc+3][jl] = v0.w;
    }
    __syncthreads();
#pragma unroll 4
    for (int k = 0; k < 32; k++) {
      float a0 = A[k][to * 2 + 0];
      float a1 = A[k][to * 2 + 1];
      float4 bv = *(const float4*)&Bs[k][tj * 4];
      acc[0][0] = fmaf(a0, bv.x, acc[0][0]);
      acc[0][1] = fmaf(a0, bv.y, acc[0][1]);
      acc[0][2] = fmaf(a0, bv.z, acc[0][2]);
      acc[0][3] = fmaf(a0, bv.w, acc[0][3]);
      acc[1][0] = fmaf(a1, bv.x, acc[1][0]);
      acc[1][1] = fmaf(a1, bv.y, acc[1][1]);
      acc[1][2] = fmaf(a1, bv.z, acc[1][2]);
      acc[1][3] = fmaf(a1, bv.w, acc[1][3]);
    }
    __syncthreads();
  }
#pragma unroll
  for (int i = 0; i < 2; i++) {
    int o = o0 + to * 2 + i;
    float gg = g[o], bb = cb[o], bo = bt[o];
    float4 v;
    float x0 = fmaf(gg, acc[i][0] + bb, bo); v.x = x0 > 0.0f ? x0 : 0.0f;
    float x1 = fmaf(gg, acc[i][1] + bb, bo); v.y = x1 > 0.0f ? x1 : 0.0f;
    float x2 = fmaf(gg, acc[i][2] + bb, bo); v.z = x2 > 0.0f ? x2 : 0.0f;
    float x3 = fmaf(gg, acc[i][3] + bb, bo); v.w = x3 > 0.0f ? x3 : 0.0f;
    *(float4*)&out1[((size_t)b * 256 + o) * 1024 + jb * 32 + tj * 4] = v;
  }
}

extern "C" void kernel_launch(void* const* d_in, const int* in_sizes, int n_in,
                              void* d_out, int out_size, void* d_ws, size_t ws_size,
                              hipStream_t stream) {
  (void)in_sizes; (void)n_in; (void)out_size; (void)ws_size;
  const float* sf    = (const float*)d_in[0];
  const float* df    = (const float*)d_in[1];
  const float* coor  = (const float*)d_in[2];
  const float* d2sw  = (const float*)d_in[3];
  const float* d2sb  = (const float*)d_in[4];
  const float* d2sg  = (const float*)d_in[5];
  const float* d2sbt = (const float*)d_in[6];
  const float* spW   = (const float*)d_in[7];
  const float* spb   = (const float*)d_in[8];
  const float* spg   = (const float*)d_in[9];
  const float* spbt  = (const float*)d_in[10];
  const float* dnW   = (const float*)d_in[11];
  const float* dnb   = (const float*)d_in[12];
  const float* dng   = (const float*)d_in[13];
  const float* dnbt  = (const float*)d_in[14];
  const float* dsw   = (const float*)d_in[15];
  const float* dsb   = (const float*)d_in[16];
  const float* dsg   = (const float*)d_in[17];
  const float* dsbt  = (const float*)d_in[18];

  float* ws   = (float*)d_ws;
  float* Pc   = ws + OFF_P;
  float* Qp   = ws + OFF_Q;
  float* SQD  = ws + OFF_SQD;
  float* SPFD = ws + OFF_SPFD;
  int*   FPS  = (int*)(ws + OFF_FPS);
  float* SD   = ws + OFF_SD;
  _Float16* XT2H = (_Float16*)(ws + OFF_XT);
  _Float16* XT2L = XT2H + (size_t)4 * NPNT * 256;
  float* Mb = ws + OFF_XT;     // M aliases XT region (XT dead after k_knnpq)
  _Float16* WPh = (_Float16*)(ws + OFF_WSP);
  _Float16* WPl = WPh + 65536;
  _Float16* WQh = WPh + 131072;
  _Float16* WQl = WPh + 196608;
  float* WDP = ws + OFF_WSP + 131072;
  u32* PKD = (u32*)(ws + OFF_P + 2097152);
  u16* PKI = (u16*)(ws + OFF_P + 2097152 + 1310720);

  float* out0 = (float*)d_out;
  float* out1 = out0 + 16384;
  float* out2 = out1 + 1048576;

  k_pre<<<dim3(1032), 256, 0, stream>>>(df, sf, coor, dnW, d2sw, d2sb, d2sg, d2sbt, dsw,
                                        XT2H, XT2L, SQD, WPh, WPl, WQh, WQl, WDP, SD,
                                        SPFD, FPS, out2);
  k_sparse_mono2<<<dim3(4, 8), 256, 0, stream>>>(sf, SPFD, FPS, spW, spg, spb, spbt, out0);
  k_knnpq<<<dim3(3072), 256, 0, stream>>>(XT2H, XT2L, SQD, SD, FPS,
                                          WPh, WPl, WQh, WQl, dng, dnb, dnbt,
                                          PKD, PKI, Pc, Qp);
  k_build_M<<<dim3(8, 16, 4), 256, 0, stream>>>(Pc, Qp, PKD, PKI, Mb);
  k_ds_gemm<<<dim3(32, 4, 4), 256, 0, stream>>>(WDP, Mb, dsb, dsg, dsbt, out1);
}